// Round 3
// baseline (1175.294 us; speedup 1.0000x reference)
//
#include <hip/hip_runtime.h>
#include <hip/hip_cooperative_groups.h>
#include <math.h>

namespace cg = cooperative_groups;

#define N 1024
#define M 128
#define NB 512
#define NT 256

struct KParams {
  const float *D, *dd, *dr, *ddep;
  const float *mu0A1, *mu0A2, *mu0B;
  const float *W1, *W2, *W3A1, *W3A2, *W4A1, *W4A2, *W3B, *W4B, *W5, *W6, *W7;
  float *DT, *PT1, *PT2, *wd1, *wd2;
  float *W3A1T, *W3A2T, *W3BT, *W4BT;
  float *muA1a, *muA1b, *muA2a, *muA2b, *muBa, *muBb, *biasb;
  float *Cp;            // 16 * N * M floats (8 MB)
  float *gsum;
  unsigned int *gcnt;
  float *out;
};

// ---------- block reductions (leading syncthreads guards red reuse) ----------
__device__ __forceinline__ float blk_max(float v, float* red, int t) {
#pragma unroll
  for (int o = 32; o; o >>= 1) v = fmaxf(v, __shfl_xor(v, o));
  __syncthreads();
  if ((t & 63) == 0) red[t >> 6] = v;
  __syncthreads();
  return fmaxf(fmaxf(red[0], red[1]), fmaxf(red[2], red[3]));
}
__device__ __forceinline__ float blk_sum(float v, float* red, int t) {
#pragma unroll
  for (int o = 32; o; o >>= 1) v += __shfl_xor(v, o);
  __syncthreads();
  if ((t & 63) == 0) red[t >> 6] = v;
  __syncthreads();
  return red[0] + red[1] + red[2] + red[3];
}

// ---------- split-K GEMM phase: Cp[r0..r0+32][0..128] = A[rows, k0..k0+klen] @ Bm ----------
__device__ __forceinline__ void gemm_phase(const float* __restrict__ A,   // [N][N] row-major (PT)
                                           const float* __restrict__ Bm,  // [N][M] (mu)
                                           float* __restrict__ Cp,        // this chunk's [N][M] slot
                                           int r0, int k0, int klen,
                                           float* smem, int t) {
  float* As = smem;          // k-major [32][36]: As[kk*36 + row]
  float* Bs = smem + 1152;   // [32][128]
  const int tr4 = (t >> 5) * 4;
  const int tc4 = (t & 31) * 4;
  const int lr = t >> 3;
  const int kb = (t & 7) * 4;
  float4 acc0 = {0,0,0,0}, acc1 = {0,0,0,0}, acc2 = {0,0,0,0}, acc3 = {0,0,0,0};
  for (int kt = 0; kt < klen; kt += 32) {
    float4 a4 = *(const float4*)&A[(size_t)(r0 + lr) * N + k0 + kt + kb];
#pragma unroll
    for (int i = 0; i < 4; i++) {
      int e = t + i * 256, br = e >> 5, bc = (e & 31) * 4;
      *(float4*)&Bs[br * 128 + bc] = *(const float4*)&Bm[(size_t)(k0 + kt + br) * M + bc];
    }
    As[(kb + 0) * 36 + lr] = a4.x;
    As[(kb + 1) * 36 + lr] = a4.y;
    As[(kb + 2) * 36 + lr] = a4.z;
    As[(kb + 3) * 36 + lr] = a4.w;
    __syncthreads();
#pragma unroll
    for (int kk = 0; kk < 32; kk++) {
      float4 av = *(const float4*)&As[kk * 36 + tr4];
      float4 bv = *(const float4*)&Bs[kk * 128 + tc4];
      acc0.x = fmaf(av.x, bv.x, acc0.x); acc0.y = fmaf(av.x, bv.y, acc0.y);
      acc0.z = fmaf(av.x, bv.z, acc0.z); acc0.w = fmaf(av.x, bv.w, acc0.w);
      acc1.x = fmaf(av.y, bv.x, acc1.x); acc1.y = fmaf(av.y, bv.y, acc1.y);
      acc1.z = fmaf(av.y, bv.z, acc1.z); acc1.w = fmaf(av.y, bv.w, acc1.w);
      acc2.x = fmaf(av.z, bv.x, acc2.x); acc2.y = fmaf(av.z, bv.y, acc2.y);
      acc2.z = fmaf(av.z, bv.z, acc2.z); acc2.w = fmaf(av.z, bv.w, acc2.w);
      acc3.x = fmaf(av.w, bv.x, acc3.x); acc3.y = fmaf(av.w, bv.y, acc3.y);
      acc3.z = fmaf(av.w, bv.z, acc3.z); acc3.w = fmaf(av.w, bv.w, acc3.w);
    }
    __syncthreads();
  }
  *(float4*)&Cp[(size_t)(r0 + tr4 + 0) * M + tc4] = acc0;
  *(float4*)&Cp[(size_t)(r0 + tr4 + 1) * M + tc4] = acc1;
  *(float4*)&Cp[(size_t)(r0 + tr4 + 2) * M + tc4] = acc2;
  *(float4*)&Cp[(size_t)(r0 + tr4 + 3) * M + tc4] = acc3;
}

// ---------- A-chain epilogue: 4 rows/block ----------
__device__ __forceinline__ void epiA_phase(const float* __restrict__ Cp,   // chain base [8][N][M]
                                           const float* __restrict__ muold,
                                           const float* __restrict__ wdv,
                                           const float* __restrict__ distv,
                                           const float* __restrict__ W3T,
                                           const float* __restrict__ W4c,
                                           const float* __restrict__ Wg,
                                           float* __restrict__ outmu,
                                           int r0, float* smem, int t) {
  float* Cs = smem;          // [4][128]
  float* swd = smem + 512;   // [4]
#pragma unroll
  for (int i = 0; i < 2; i++) {
    int e = t + i * 256, r = e >> 7, m = e & 127;
    float s = 0.f;
#pragma unroll
    for (int kc = 0; kc < 8; kc++) s += Cp[((size_t)kc * N + r0 + r) * M + m];
    Cs[r * 128 + m] = s;
  }
  {
    int row = t >> 6, l = t & 63;
    const float* mo = muold + (size_t)(r0 + row) * M;
    float sp = fmaf(mo[l], Wg[l], mo[l + 64] * Wg[l + 64]);
#pragma unroll
    for (int o = 32; o; o >>= 1) sp += __shfl_xor(sp, o);
    if (l == 0) swd[row] = wdv[r0 + row] * fmaxf(sp, 0.f);
  }
  __syncthreads();
  int row = t >> 6, cc = (t & 63) * 2;
  float2 acc = {0.f, 0.f};
#pragma unroll 8
  for (int m = 0; m < 128; m++) {
    float a = Cs[row * 128 + m];
    float2 wv = *(const float2*)&W3T[(m + 1) * 128 + cc];
    acc.x = fmaf(a, wv.x, acc.x);
    acc.y = fmaf(a, wv.y, acc.y);
  }
  float2 w30 = *(const float2*)&W3T[cc];
  float2 w4v = *(const float2*)&W4c[cc];
  float sv = swd[row], dv = distv[r0 + row];
  float2 o;
  o.x = fmaxf(fmaf(sv, w30.x, fmaf(dv, w4v.x, acc.x)), 0.f);
  o.y = fmaxf(fmaf(sv, w30.y, fmaf(dv, w4v.y, acc.y)), 0.f);
  *(float2*)&outmu[(size_t)(r0 + row) * M + cc] = o;
}

// ---------- B-chain epilogue: 2 rows/block; last iter fuses final reduction ----------
__device__ __forceinline__ void epiB_phase(const float* __restrict__ Cp,   // [16][N][M]
                                           const float* __restrict__ W3BT,
                                           const float* __restrict__ biasb,
                                           float* __restrict__ outmu,
                                           int r0, float* smem, int t, bool last,
                                           const float* __restrict__ W7,
                                           float* gsum, unsigned int* gcnt, float* out) {
  float* Cs = smem;   // [2][128]
  {
    int r = t >> 7, m = t & 127;
    float s = 0.f;
#pragma unroll
    for (int kc = 0; kc < 16; kc++) s += Cp[((size_t)kc * N + r0 + r) * M + m];
    Cs[r * 128 + m] = s;
  }
  __syncthreads();
  int row = t >> 7, col = t & 127;
  float acc = 0.f;
#pragma unroll 8
  for (int m = 0; m < 128; m++)
    acc = fmaf(Cs[row * 128 + m], W3BT[m * 128 + col], acc);
  float o = fmaxf(acc + biasb[(size_t)(r0 + row) * M + col], 0.f);
  if (!last) {
    outmu[(size_t)(r0 + row) * M + col] = o;
  } else {
    float part = o * W7[col];
#pragma unroll
    for (int s = 32; s; s >>= 1) part += __shfl_xor(part, s);
    __syncthreads();
    if ((t & 63) == 0) smem[256 + (t >> 6)] = part;
    __syncthreads();
    if (t == 0) {
      float bs = smem[256] + smem[257] + smem[258] + smem[259];
      atomicAdd(gsum, bs);
      __threadfence();
      unsigned int old = atomicAdd(gcnt, 1u);
      if (old == NB - 1) {
        float tot = atomicAdd(gsum, 0.f);
        out[0] = fmaxf(tot, 0.f);
      }
    }
  }
}

// ---------- bias rows (2/block), merged into B-G0 phase ----------
__device__ __forceinline__ void bias_phase(const float* __restrict__ A1f,
                                           const float* __restrict__ A2f,
                                           const float* __restrict__ W4BT,
                                           float* __restrict__ biasb, int r0, int t) {
  int row = t >> 7, col = t & 127;
  const float* a1 = A1f + (size_t)(r0 + row) * M;
  const float* a2 = A2f + (size_t)(r0 + row) * M;
  float acc = 0.f;
#pragma unroll 4
  for (int c = 0; c < 128; c++) acc = fmaf(a1[c], W4BT[c * 128 + col], acc);
#pragma unroll 4
  for (int c = 0; c < 128; c++) acc = fmaf(a2[c], W4BT[(c + 128) * 128 + col], acc);
  biasb[(size_t)(r0 + row) * M + col] = acc;
}

// ================= mega kernel =================
__global__ __launch_bounds__(NT, 2) void mega(KParams P) {
  cg::grid_group grid = cg::this_grid();
  __shared__ float smem[5248];
  const int t = threadIdx.x;
  const int bid = blockIdx.x;

  // ---- P0: transpose D -> DT; zero final accumulators
  if (bid == 0 && t == 0) { *P.gsum = 0.f; *P.gcnt = 0u; }
  {
    float* tile = smem;
    int tx = t & 31, ty = t >> 5;
#pragma unroll
    for (int rep = 0; rep < 2; rep++) {
      int T = bid + rep * NB;
      int bx = (T & 31) * 32, by = (T >> 5) * 32;
#pragma unroll
      for (int i = 0; i < 4; i++)
        tile[(ty + i * 8) * 33 + tx] = P.D[(size_t)(by + ty + i * 8) * N + bx + tx];
      __syncthreads();
#pragma unroll
      for (int i = 0; i < 4; i++)
        P.DT[(size_t)(bx + ty + i * 8) * N + by + tx] = tile[tx * 33 + ty + i * 8];
      __syncthreads();
    }
  }
  grid.sync();

  // ---- P1: weight transposes + edge scores/dual softmax/wd
  {
    int idx = bid * NT + t;
    const float* in = nullptr; float* op = nullptr; int cols = 0, o = 0;
    if (idx < 16512)      { in = P.W3A1; op = P.W3A1T; cols = 129; o = idx; }
    else if (idx < 33024) { in = P.W3A2; op = P.W3A2T; cols = 129; o = idx - 16512; }
    else if (idx < 49408) { in = P.W3B;  op = P.W3BT;  cols = 128; o = idx - 33024; }
    else if (idx < 82176) { in = P.W4B;  op = P.W4BT;  cols = 256; o = idx - 49408; }
    if (in) { int r = o & 127, c = o >> 7; op[o] = in[r * cols + c]; }
  }
  {
    float* red = smem;
    float4* wp = (float4*)(smem + 4);
    if (t < 128) {
      float4 pw;
      pw.x = P.W2[t * 3 + 0]; pw.y = P.W2[t * 3 + 1]; pw.z = P.W2[t * 3 + 2]; pw.w = P.W1[t];
      wp[t] = pw;
    }
    __syncthreads();
    for (int rep = 0; rep < 2; rep++) {
      int v = bid + rep * NB;
      float yv = P.dd[v];
      float x[4], z[4], g[4] = {0.f, 0.f, 0.f, 0.f};
#pragma unroll
      for (int i = 0; i < 4; i++) {
        int u = t + i * 256;
        x[i] = P.DT[(size_t)v * N + u];
        z[i] = P.dd[u];
      }
#pragma unroll 2
      for (int k = 0; k < 128; k++) {
        float4 wk = wp[k];
        float cv = yv * wk.z;
#pragma unroll
        for (int i = 0; i < 4; i++) {
          float h = fmaf(x[i], wk.x, fmaf(z[i], wk.y, cv));
          g[i] = fmaf(fmaxf(h, 0.f), wk.w, g[i]);
        }
      }
#pragma unroll
      for (int i = 0; i < 4; i++)
        if (t + i * 256 == v) g[i] = -INFINITY;
      float m = fmaxf(fmaxf(g[0], g[1]), fmaxf(g[2], g[3]));
      m = blk_max(m, red, t);
      float er[4], es[4], sr = 0.f, ss = 0.f;
#pragma unroll
      for (int i = 0; i < 4; i++) {
        er[i] = expf((g[i] - m) * 0.1f);   // raw /TAU
        es[i] = expf((g[i] - m) * 1e-4f);  // scaled /(1000*TAU)
        sr += er[i]; ss += es[i];
      }
      sr = blk_sum(sr, red, t);
      ss = blk_sum(ss, red, t);
      float ir = 1.f / sr, is = 1.f / ss;
      float a1 = 0.f, a2 = 0.f;
#pragma unroll
      for (int i = 0; i < 4; i++) {
        int u = t + i * 256;
        float pr = er[i] * ir, ps = es[i] * is;
        P.PT2[(size_t)v * N + u] = pr;
        P.PT1[(size_t)v * N + u] = ps;
        a1 += ps * x[i];
        a2 += pr * x[i];
      }
      a1 = blk_sum(a1, red, t);
      a2 = blk_sum(a2, red, t);
      if (t == 0) { P.wd1[v] = a1; P.wd2[v] = a2; }
    }
  }
  grid.sync();

  // ---- A chains: 4 iterations, 2 chains concurrent
  {
    const int chain = bid >> 8;
    const int rowblk = (bid >> 3) & 31;
    const int kc = bid & 7;
    const int r0g = rowblk * 32, k0 = kc * 128;
    const float* PT = chain ? P.PT2 : P.PT1;
    float* CpSlot = P.Cp + (size_t)(chain * 8 + kc) * N * M;
    const float* CpChain = P.Cp + (size_t)(chain * 8) * N * M;
    const float* wdv = chain ? P.wd2 : P.wd1;
    const float* distv = chain ? P.ddep : P.dr;
    const float* W3T = chain ? P.W3A2T : P.W3A1T;
    const float* W4c = chain ? P.W4A2 : P.W4A1;
    const float* Wg = chain ? P.W6 : P.W5;
    const int er0 = (bid & 255) * 4;
    const float* cur = chain ? P.mu0A2 : P.mu0A1;
    for (int it = 0; it < 4; it++) {
      gemm_phase(PT, cur, CpSlot, r0g, k0, 128, smem, t);
      grid.sync();
      float* nxt = chain ? ((it & 1) ? P.muA2b : P.muA2a)
                         : ((it & 1) ? P.muA1b : P.muA1a);
      epiA_phase(CpChain, cur, wdv, distv, W3T, W4c, Wg, nxt, er0, smem, t);
      grid.sync();
      cur = nxt;
    }
  }

  // ---- bias (merged with B-G0) + B chain: 4 iterations
  {
    const int rowblk = bid >> 4, kc = bid & 15;
    const int r0g = rowblk * 32, k0 = kc * 64;
    float* CpSlot = P.Cp + (size_t)kc * N * M;
    const int er0 = bid * 2;
    const float* cur = P.mu0B;
    for (int it = 0; it < 4; it++) {
      if (it == 0) bias_phase(P.muA1b, P.muA2b, P.W4BT, P.biasb, er0, t);
      gemm_phase(P.PT1, cur, CpSlot, r0g, k0, 64, smem, t);
      grid.sync();
      float* nxt = (it & 1) ? P.muBb : P.muBa;
      epiB_phase(P.Cp, P.W3BT, P.biasb, nxt, er0, smem, t, it == 3,
                 P.W7, P.gsum, P.gcnt, P.out);
      if (it < 3) grid.sync();
      cur = nxt;
    }
  }
}

// ======================================================================
// Fallback path: round-2 multi-kernel pipeline (used if coop launch fails)
// ======================================================================
__global__ __launch_bounds__(256) void k_transpose_d(const float* __restrict__ D,
                                                     float* __restrict__ DT) {
  __shared__ float tile[32][33];
  int tx = threadIdx.x, ty = threadIdx.y;
  int bx = blockIdx.x * 32, by = blockIdx.y * 32;
#pragma unroll
  for (int i = 0; i < 4; i++)
    tile[ty + i * 8][tx] = D[(by + ty + i * 8) * N + bx + tx];
  __syncthreads();
#pragma unroll
  for (int i = 0; i < 4; i++)
    DT[(bx + ty + i * 8) * N + by + tx] = tile[tx][ty + i * 8];
}

__global__ __launch_bounds__(256) void k_prep_w(const float* __restrict__ W3A1, const float* __restrict__ W3A2,
                         const float* __restrict__ W3B, const float* __restrict__ W4B,
                         float* __restrict__ oA1, float* __restrict__ oA2,
                         float* __restrict__ oB, float* __restrict__ o4B) {
  int idx = blockIdx.x * 256 + threadIdx.x;
  const float* in; float* out; int cols; int o;
  if (idx < 16512)      { in = W3A1; out = oA1; cols = 129; o = idx; }
  else if (idx < 33024) { in = W3A2; out = oA2; cols = 129; o = idx - 16512; }
  else if (idx < 49408) { in = W3B;  out = oB;  cols = 128; o = idx - 33024; }
  else if (idx < 82176) { in = W4B;  out = o4B; cols = 256; o = idx - 49408; }
  else return;
  int r = o & 127, c = o >> 7;
  out[o] = in[r * cols + c];
}

__global__ __launch_bounds__(256) void k_edge(const float* __restrict__ DT,
                                              const float* __restrict__ dd,
                                              const float* __restrict__ W1,
                                              const float* __restrict__ W2,
                                              float* __restrict__ PT1, float* __restrict__ PT2,
                                              float* __restrict__ wd1, float* __restrict__ wd2) {
  __shared__ float4 wp[128];
  __shared__ float red[4];
  int t = threadIdx.x, v = blockIdx.x;
  if (t < 128) {
    float4 p;
    p.x = W2[t * 3 + 0]; p.y = W2[t * 3 + 1]; p.z = W2[t * 3 + 2]; p.w = W1[t];
    wp[t] = p;
  }
  __syncthreads();
  float yv = dd[v];
  float x[4], z[4], g[4] = {0.f, 0.f, 0.f, 0.f};
#pragma unroll
  for (int i = 0; i < 4; i++) {
    int u = t + i * 256;
    x[i] = DT[v * N + u];
    z[i] = dd[u];
  }
#pragma unroll 2
  for (int k = 0; k < 128; k++) {
    float4 wk = wp[k];
    float cv = yv * wk.z;
#pragma unroll
    for (int i = 0; i < 4; i++) {
      float h = fmaf(x[i], wk.x, fmaf(z[i], wk.y, cv));
      g[i] = fmaf(fmaxf(h, 0.f), wk.w, g[i]);
    }
  }
#pragma unroll
  for (int i = 0; i < 4; i++)
    if (t + i * 256 == v) g[i] = -INFINITY;
  float m = fmaxf(fmaxf(g[0], g[1]), fmaxf(g[2], g[3]));
  m = blk_max(m, red, t);
  float er[4], es[4], sr = 0.f, ss = 0.f;
#pragma unroll
  for (int i = 0; i < 4; i++) {
    er[i] = expf((g[i] - m) * 0.1f);
    es[i] = expf((g[i] - m) * 1e-4f);
    sr += er[i]; ss += es[i];
  }
  sr = blk_sum(sr, red, t);
  ss = blk_sum(ss, red, t);
  float ir = 1.f / sr, is = 1.f / ss;
  float a1 = 0.f, a2 = 0.f;
#pragma unroll
  for (int i = 0; i < 4; i++) {
    int u = t + i * 256;
    float pr = er[i] * ir, ps = es[i] * is;
    PT2[v * N + u] = pr;
    PT1[v * N + u] = ps;
    a1 += ps * x[i];
    a2 += pr * x[i];
  }
  a1 = blk_sum(a1, red, t);
  a2 = blk_sum(a2, red, t);
  if (t == 0) { wd1[v] = a1; wd2[v] = a2; }
}

__global__ __launch_bounds__(256) void k_gemm(const float* __restrict__ PT0, const float* __restrict__ mu_0, float* __restrict__ C_0,
                                              const float* __restrict__ PT1p, const float* __restrict__ mu_1, float* __restrict__ C_1) {
  int z = blockIdx.z;
  const float* PT = z ? PT1p : PT0;
  const float* mu = z ? mu_1 : mu_0;
  float* C = z ? C_1 : C_0;
  __shared__ float As[32][18];
  __shared__ float Bs[32][128];
  int t = threadIdx.x;
  int r0 = blockIdx.x * 16, k0 = blockIdx.y * 256;
  int tr = t >> 5, tc = t & 31;
  int lr = t >> 4, lk = t & 15;
  float4 acc0 = {0, 0, 0, 0}, acc1 = {0, 0, 0, 0};
  for (int kt = 0; kt < 256; kt += 32) {
    const float* psrc = &PT[(r0 + lr) * N + k0 + kt + lk];
    float a0 = psrc[0], a1 = psrc[16];
#pragma unroll
    for (int i = 0; i < 4; i++) {
      int e = t + i * 256, br = e >> 5, bc = e & 31;
      *(float4*)&Bs[br][bc * 4] = *(const float4*)&mu[(k0 + kt + br) * M + bc * 4];
    }
    As[lk][lr] = a0;
    As[lk + 16][lr] = a1;
    __syncthreads();
#pragma unroll
    for (int kk = 0; kk < 32; kk++) {
      float2 av = *(const float2*)&As[kk][tr * 2];
      float4 b = *(const float4*)&Bs[kk][tc * 4];
      acc0.x = fmaf(av.x, b.x, acc0.x); acc0.y = fmaf(av.x, b.y, acc0.y);
      acc0.z = fmaf(av.x, b.z, acc0.z); acc0.w = fmaf(av.x, b.w, acc0.w);
      acc1.x = fmaf(av.y, b.x, acc1.x); acc1.y = fmaf(av.y, b.y, acc1.y);
      acc1.z = fmaf(av.y, b.z, acc1.z); acc1.w = fmaf(av.y, b.w, acc1.w);
    }
    __syncthreads();
  }
  float* dst = C + ((size_t)blockIdx.y * N + r0 + tr * 2) * M + tc * 4;
  *(float4*)dst = acc0;
  *(float4*)(dst + M) = acc1;
}

__global__ __launch_bounds__(256) void k_epi(int modeA,
    const float* __restrict__ Cp_0, const float* __restrict__ muold_0,
    const float* __restrict__ wd_0, const float* __restrict__ dist_0,
    const float* __restrict__ W3T_0, const float* __restrict__ W4c_0,
    const float* __restrict__ Wg_0, float* __restrict__ out_0,
    const float* __restrict__ Cp_1, const float* __restrict__ muold_1,
    const float* __restrict__ wd_1, const float* __restrict__ dist_1,
    const float* __restrict__ W3T_1, const float* __restrict__ W4c_1,
    const float* __restrict__ Wg_1, float* __restrict__ out_1,
    const float* __restrict__ bias) {
  int z = blockIdx.z;
  const float* Cp = z ? Cp_1 : Cp_0;
  const float* muold = z ? muold_1 : muold_0;
  const float* wd = z ? wd_1 : wd_0;
  const float* dist = z ? dist_1 : dist_0;
  const float* W3T = z ? W3T_1 : W3T_0;
  const float* W4c = z ? W4c_1 : W4c_0;
  const float* Wg = z ? Wg_1 : Wg_0;
  float* out = z ? out_1 : out_0;
  __shared__ float Cs[8][129];
  __shared__ float swd[8];
  int t = threadIdx.x, r0 = blockIdx.x * 8;
#pragma unroll
  for (int i = 0; i < 4; i++) {
    int e = t + i * 256, r = e >> 7, m = e & 127;
    float s = 0.f;
#pragma unroll
    for (int c = 0; c < 4; c++) s += Cp[((size_t)c * N + r0 + r) * M + m];
    Cs[r][m] = s;
  }
  if (modeA) {
    int row = t >> 5, g = t & 31;
    const float* mo = muold + (r0 + row) * M + g * 4;
    float sp = 0.f;
#pragma unroll
    for (int j = 0; j < 4; j++) sp = fmaf(mo[j], Wg[g * 4 + j], sp);
#pragma unroll
    for (int o = 16; o; o >>= 1) sp += __shfl_xor(sp, o);
    if (g == 0) swd[row] = wd[r0 + row] * fmaxf(sp, 0.f);
  }
  __syncthreads();
  int tr = t >> 5, tc = t & 31;
  float4 acc = {0, 0, 0, 0};
  int off = modeA ? 1 : 0;
#pragma unroll 8
  for (int m = 0; m < 128; m++) {
    float a = Cs[tr][m];
    float4 wv = *(const float4*)&W3T[(m + off) * 128 + tc * 4];
    acc.x = fmaf(a, wv.x, acc.x); acc.y = fmaf(a, wv.y, acc.y);
    acc.z = fmaf(a, wv.z, acc.z); acc.w = fmaf(a, wv.w, acc.w);
  }
  int ra = r0 + tr;
  float4 e0;
  if (modeA) {
    float4 w30 = *(const float4*)&W3T[tc * 4];
    float4 w4v = *(const float4*)&W4c[tc * 4];
    float s0 = swd[tr];
    float d0 = dist[ra];
    e0.x = s0 * w30.x + d0 * w4v.x; e0.y = s0 * w30.y + d0 * w4v.y;
    e0.z = s0 * w30.z + d0 * w4v.z; e0.w = s0 * w30.w + d0 * w4v.w;
  } else {
    e0 = *(const float4*)&bias[ra * M + tc * 4];
  }
  float4 o0;
  o0.x = fmaxf(acc.x + e0.x, 0.f); o0.y = fmaxf(acc.y + e0.y, 0.f);
  o0.z = fmaxf(acc.z + e0.z, 0.f); o0.w = fmaxf(acc.w + e0.w, 0.f);
  *(float4*)&out[ra * M + tc * 4] = o0;
}

__global__ __launch_bounds__(256) void k_bias(const float* __restrict__ A1,
                                              const float* __restrict__ A2,
                                              const float* __restrict__ W4BT,
                                              float* __restrict__ bias) {
  __shared__ float Cs[16][257];
  int t = threadIdx.x, r0 = blockIdx.x * 16;
#pragma unroll
  for (int i = 0; i < 16; i++) {
    int e = t + i * 256, r = e >> 8, c = e & 255;
    Cs[r][c] = (c < 128) ? A1[(r0 + r) * M + c] : A2[(r0 + r) * M + (c - 128)];
  }
  __syncthreads();
  int tr = t >> 5, tc = t & 31;
  float4 acc0 = {0, 0, 0, 0}, acc1 = {0, 0, 0, 0};
#pragma unroll 4
  for (int m = 0; m < 256; m++) {
    float a0 = Cs[tr * 2][m], a1 = Cs[tr * 2 + 1][m];
    float4 wv = *(const float4*)&W4BT[m * 128 + tc * 4];
    acc0.x = fmaf(a0, wv.x, acc0.x); acc0.y = fmaf(a0, wv.y, acc0.y);
    acc0.z = fmaf(a0, wv.z, acc0.z); acc0.w = fmaf(a0, wv.w, acc0.w);
    acc1.x = fmaf(a1, wv.x, acc1.x); acc1.y = fmaf(a1, wv.y, acc1.y);
    acc1.z = fmaf(a1, wv.z, acc1.z); acc1.w = fmaf(a1, wv.w, acc1.w);
  }
  int ra = r0 + tr * 2, rb = ra + 1;
  *(float4*)&bias[ra * M + tc * 4] = acc0;
  *(float4*)&bias[rb * M + tc * 4] = acc1;
}

__global__ __launch_bounds__(1024) void k_final(const float* __restrict__ mu,
                                                const float* __restrict__ W7,
                                                float* __restrict__ out) {
  __shared__ float red[1024];
  int t = threadIdx.x;
  int j = t & 127, q = t >> 7;
  float acc = 0.f;
  for (int v = q; v < N; v += 8) acc += mu[v * M + j];
  red[t] = acc;
  __syncthreads();
  float tot = 0.f;
  if (t < 128) {
    float cs = 0.f;
#pragma unroll
    for (int s = 0; s < 8; s++) cs += red[s * 128 + t];
    tot = cs * W7[t];
#pragma unroll
    for (int o = 32; o; o >>= 1) tot += __shfl_xor(tot, o);
  }
  __syncthreads();
  if (t == 0) red[0] = tot;
  if (t == 64) red[1] = tot;
  __syncthreads();
  if (t == 0) out[0] = fmaxf(red[0] + red[1], 0.f);
}

extern "C" void kernel_launch(void* const* d_in, const int* in_sizes, int n_in,
                              void* d_out, int out_size, void* d_ws, size_t ws_size,
                              hipStream_t stream) {
  (void)in_sizes; (void)n_in; (void)out_size; (void)ws_size;
  const float* D     = (const float*)d_in[0];
  const float* dd    = (const float*)d_in[1];
  const float* dr    = (const float*)d_in[2];
  const float* ddep  = (const float*)d_in[3];
  const float* mu0A1 = (const float*)d_in[4];
  const float* mu0A2 = (const float*)d_in[5];
  const float* mu0B  = (const float*)d_in[6];
  const float* W1    = (const float*)d_in[7];
  const float* W2    = (const float*)d_in[8];
  const float* W3A1  = (const float*)d_in[9];
  const float* W3A2  = (const float*)d_in[10];
  const float* W4A1  = (const float*)d_in[11];
  const float* W4A2  = (const float*)d_in[12];
  const float* W3B   = (const float*)d_in[13];
  const float* W4B   = (const float*)d_in[14];
  const float* W5    = (const float*)d_in[15];
  const float* W6    = (const float*)d_in[16];
  const float* W7    = (const float*)d_in[17];

  float* w = (float*)d_ws;
  size_t o = 0;
  auto alloc = [&](size_t n) { float* p = w + o; o += n; return p; };
  float* Cp    = alloc((size_t)16 * N * M);     // 8 MB partials (A: 2x8 slots, B: 16 slots)
  float* DT    = alloc((size_t)N * N);
  float* PT1   = alloc((size_t)N * N);
  float* PT2   = alloc((size_t)N * N);
  float* wd1   = alloc(N);
  float* wd2   = alloc(N);
  float* W3A1T = alloc(129 * 128);
  float* W3A2T = alloc(129 * 128);
  float* W3BT  = alloc(128 * 128);
  float* W4BT  = alloc(256 * 128);
  float* muA1a = alloc((size_t)N * M); float* muA1b = alloc((size_t)N * M);
  float* muA2a = alloc((size_t)N * M); float* muA2b = alloc((size_t)N * M);
  float* muBa  = alloc((size_t)N * M); float* muBb  = alloc((size_t)N * M);
  float* biasb = alloc((size_t)N * M);
  float* gsum  = alloc(1);
  unsigned int* gcnt = (unsigned int*)alloc(1);

  KParams p;
  p.D = D; p.dd = dd; p.dr = dr; p.ddep = ddep;
  p.mu0A1 = mu0A1; p.mu0A2 = mu0A2; p.mu0B = mu0B;
  p.W1 = W1; p.W2 = W2; p.W3A1 = W3A1; p.W3A2 = W3A2;
  p.W4A1 = W4A1; p.W4A2 = W4A2; p.W3B = W3B; p.W4B = W4B;
  p.W5 = W5; p.W6 = W6; p.W7 = W7;
  p.DT = DT; p.PT1 = PT1; p.PT2 = PT2; p.wd1 = wd1; p.wd2 = wd2;
  p.W3A1T = W3A1T; p.W3A2T = W3A2T; p.W3BT = W3BT; p.W4BT = W4BT;
  p.muA1a = muA1a; p.muA1b = muA1b; p.muA2a = muA2a; p.muA2b = muA2b;
  p.muBa = muBa; p.muBb = muBb; p.biasb = biasb;
  p.Cp = Cp; p.gsum = gsum; p.gcnt = gcnt; p.out = (float*)d_out;

  void* args[] = { (void*)&p };
  hipError_t err = hipLaunchCooperativeKernel((const void*)mega, dim3(NB), dim3(NT),
                                              args, 0, stream);
  if (err == hipSuccess) return;

  // ---------- fallback: multi-kernel pipeline ----------
  k_transpose_d<<<dim3(32, 32), dim3(32, 8), 0, stream>>>(D, DT);
  k_prep_w<<<321, 256, 0, stream>>>(W3A1, W3A2, W3B, W4B, W3A1T, W3A2T, W3BT, W4BT);
  k_edge<<<N, 256, 0, stream>>>(DT, dd, W1, W2, PT1, PT2, wd1, wd2);
  float* Cp0 = Cp;
  float* Cp1 = Cp + 4 * N * M;
  const float* cur1 = mu0A1;
  const float* cur2 = mu0A2;
  float* b1[2] = {muA1a, muA1b};
  float* b2[2] = {muA2a, muA2b};
  for (int t = 0; t < 4; t++) {
    k_gemm<<<dim3(64, 4, 2), 256, 0, stream>>>(PT1, cur1, Cp0, PT2, cur2, Cp1);
    k_epi<<<dim3(128, 1, 2), 256, 0, stream>>>(1,
        Cp0, cur1, wd1, dr,   W3A1T, W4A1, W5, b1[t & 1],
        Cp1, cur2, wd2, ddep, W3A2T, W4A2, W6, b2[t & 1], (const float*)nullptr);
    cur1 = b1[t & 1];
    cur2 = b2[t & 1];
  }
  k_bias<<<64, 256, 0, stream>>>(cur1, cur2, W4BT, biasb);
  const float* curB = mu0B;
  float* bB[2] = {muBa, muBb};
  for (int t = 0; t < 4; t++) {
    k_gemm<<<dim3(64, 4, 1), 256, 0, stream>>>(PT1, curB, Cp0, PT1, curB, Cp0);
    k_epi<<<dim3(128, 1, 1), 256, 0, stream>>>(0,
        Cp0, (const float*)nullptr, (const float*)nullptr, (const float*)nullptr,
        W3BT, (const float*)nullptr, (const float*)nullptr, bB[t & 1],
        (const float*)nullptr, (const float*)nullptr, (const float*)nullptr, (const float*)nullptr,
        (const float*)nullptr, (const float*)nullptr, (const float*)nullptr, (float*)nullptr,
        biasb);
    curB = bB[t & 1];
  }
  k_final<<<1, 1024, 0, stream>>>(curB, W7, (float*)d_out);
}

// Round 4
// 738.875 us; speedup vs baseline: 1.5907x; 1.5907x over previous
//
#include <hip/hip_runtime.h>
#include <math.h>

#define N 1024
#define M 128
#define NB 512
#define NT 256

struct KParams {
  const float *D, *dd, *dr, *ddep;
  const float *mu0A1, *mu0A2, *mu0B;
  const float *W1, *W2, *W3A1, *W3A2, *W4A1, *W4A2, *W3B, *W4B, *W5, *W6, *W7;
  float *DT, *PT1, *PT2, *wd1, *wd2;
  float *W3A1T, *W3A2T, *W3BT, *W4BT;
  float *muA1a, *muA1b, *muA2a, *muA2b, *muBa, *muBb, *biasb;
  float *Cp;            // 16 * N * M floats (8 MB)
  float *gsum;
  unsigned int *gcnt;
  unsigned int *bar;    // [0]=gen, [16]=master, [32+s*16]=sub s (s=0..7)
  float *out;
};

// ---------- fast two-level grid barrier (generation-based, self-cleaning) ----------
__device__ __forceinline__ void gbar(unsigned int* bar, int t, int bid) {
  __syncthreads();
  if (t == 0) {
    __threadfence();  // release: write back L2 so peers on other XCDs see our data
    unsigned int g = __hip_atomic_load(&bar[0], __ATOMIC_RELAXED, __HIP_MEMORY_SCOPE_AGENT);
    unsigned int* sub = &bar[32 + (bid & 7) * 16];
    if (__hip_atomic_fetch_add(sub, 1u, __ATOMIC_RELEASE, __HIP_MEMORY_SCOPE_AGENT) == (NB / 8 - 1)) {
      __hip_atomic_store(sub, 0u, __ATOMIC_RELAXED, __HIP_MEMORY_SCOPE_AGENT);
      if (__hip_atomic_fetch_add(&bar[16], 1u, __ATOMIC_RELEASE, __HIP_MEMORY_SCOPE_AGENT) == 7u) {
        __hip_atomic_store(&bar[16], 0u, __ATOMIC_RELAXED, __HIP_MEMORY_SCOPE_AGENT);
        __hip_atomic_fetch_add(&bar[0], 1u, __ATOMIC_RELEASE, __HIP_MEMORY_SCOPE_AGENT);
      } else {
        while (__hip_atomic_load(&bar[0], __ATOMIC_RELAXED, __HIP_MEMORY_SCOPE_AGENT) == g)
          __builtin_amdgcn_s_sleep(2);
      }
    } else {
      while (__hip_atomic_load(&bar[0], __ATOMIC_RELAXED, __HIP_MEMORY_SCOPE_AGENT) == g)
        __builtin_amdgcn_s_sleep(2);
    }
    __threadfence();  // acquire: invalidate L1/L2 so we read peers' fresh data
  }
  __syncthreads();
}

// ---------- block reductions ----------
__device__ __forceinline__ float blk_max(float v, float* red, int t) {
#pragma unroll
  for (int o = 32; o; o >>= 1) v = fmaxf(v, __shfl_xor(v, o));
  __syncthreads();
  if ((t & 63) == 0) red[t >> 6] = v;
  __syncthreads();
  return fmaxf(fmaxf(red[0], red[1]), fmaxf(red[2], red[3]));
}
__device__ __forceinline__ float blk_sum(float v, float* red, int t) {
#pragma unroll
  for (int o = 32; o; o >>= 1) v += __shfl_xor(v, o);
  __syncthreads();
  if ((t & 63) == 0) red[t >> 6] = v;
  __syncthreads();
  return red[0] + red[1] + red[2] + red[3];
}

// ---------- split-K GEMM phase ----------
__device__ __forceinline__ void gemm_phase(const float* __restrict__ A,
                                           const float* __restrict__ Bm,
                                           float* __restrict__ Cp,
                                           int r0, int k0, int klen,
                                           float* smem, int t) {
  float* As = smem;          // k-major [32][36]
  float* Bs = smem + 1152;   // [32][128]
  const int tr4 = (t >> 5) * 4;
  const int tc4 = (t & 31) * 4;
  const int lr = t >> 3;
  const int kb = (t & 7) * 4;
  float4 acc0 = {0,0,0,0}, acc1 = {0,0,0,0}, acc2 = {0,0,0,0}, acc3 = {0,0,0,0};
  for (int kt = 0; kt < klen; kt += 32) {
    float4 a4 = *(const float4*)&A[(size_t)(r0 + lr) * N + k0 + kt + kb];
#pragma unroll
    for (int i = 0; i < 4; i++) {
      int e = t + i * 256, br = e >> 5, bc = (e & 31) * 4;
      *(float4*)&Bs[br * 128 + bc] = *(const float4*)&Bm[(size_t)(k0 + kt + br) * M + bc];
    }
    As[(kb + 0) * 36 + lr] = a4.x;
    As[(kb + 1) * 36 + lr] = a4.y;
    As[(kb + 2) * 36 + lr] = a4.z;
    As[(kb + 3) * 36 + lr] = a4.w;
    __syncthreads();
#pragma unroll
    for (int kk = 0; kk < 32; kk++) {
      float4 av = *(const float4*)&As[kk * 36 + tr4];
      float4 bv = *(const float4*)&Bs[kk * 128 + tc4];
      acc0.x = fmaf(av.x, bv.x, acc0.x); acc0.y = fmaf(av.x, bv.y, acc0.y);
      acc0.z = fmaf(av.x, bv.z, acc0.z); acc0.w = fmaf(av.x, bv.w, acc0.w);
      acc1.x = fmaf(av.y, bv.x, acc1.x); acc1.y = fmaf(av.y, bv.y, acc1.y);
      acc1.z = fmaf(av.y, bv.z, acc1.z); acc1.w = fmaf(av.y, bv.w, acc1.w);
      acc2.x = fmaf(av.z, bv.x, acc2.x); acc2.y = fmaf(av.z, bv.y, acc2.y);
      acc2.z = fmaf(av.z, bv.z, acc2.z); acc2.w = fmaf(av.z, bv.w, acc2.w);
      acc3.x = fmaf(av.w, bv.x, acc3.x); acc3.y = fmaf(av.w, bv.y, acc3.y);
      acc3.z = fmaf(av.w, bv.z, acc3.z); acc3.w = fmaf(av.w, bv.w, acc3.w);
    }
    __syncthreads();
  }
  *(float4*)&Cp[(size_t)(r0 + tr4 + 0) * M + tc4] = acc0;
  *(float4*)&Cp[(size_t)(r0 + tr4 + 1) * M + tc4] = acc1;
  *(float4*)&Cp[(size_t)(r0 + tr4 + 2) * M + tc4] = acc2;
  *(float4*)&Cp[(size_t)(r0 + tr4 + 3) * M + tc4] = acc3;
}

// ---------- A-chain epilogue: 4 rows/block ----------
__device__ __forceinline__ void epiA_phase(const float* __restrict__ Cp,
                                           const float* __restrict__ muold,
                                           const float* __restrict__ wdv,
                                           const float* __restrict__ distv,
                                           const float* __restrict__ W3T,
                                           const float* __restrict__ W4c,
                                           const float* __restrict__ Wg,
                                           float* __restrict__ outmu,
                                           int r0, float* smem, int t) {
  float* Cs = smem;          // [4][128]
  float* swd = smem + 512;   // [4]
#pragma unroll
  for (int i = 0; i < 2; i++) {
    int e = t + i * 256, r = e >> 7, m = e & 127;
    float s = 0.f;
#pragma unroll
    for (int kc = 0; kc < 8; kc++) s += Cp[((size_t)kc * N + r0 + r) * M + m];
    Cs[r * 128 + m] = s;
  }
  {
    int row = t >> 6, l = t & 63;
    const float* mo = muold + (size_t)(r0 + row) * M;
    float sp = fmaf(mo[l], Wg[l], mo[l + 64] * Wg[l + 64]);
#pragma unroll
    for (int o = 32; o; o >>= 1) sp += __shfl_xor(sp, o);
    if (l == 0) swd[row] = wdv[r0 + row] * fmaxf(sp, 0.f);
  }
  __syncthreads();
  int row = t >> 6, cc = (t & 63) * 2;
  float2 acc = {0.f, 0.f};
#pragma unroll 8
  for (int m = 0; m < 128; m++) {
    float a = Cs[row * 128 + m];
    float2 wv = *(const float2*)&W3T[(m + 1) * 128 + cc];
    acc.x = fmaf(a, wv.x, acc.x);
    acc.y = fmaf(a, wv.y, acc.y);
  }
  float2 w30 = *(const float2*)&W3T[cc];
  float2 w4v = *(const float2*)&W4c[cc];
  float sv = swd[row], dv = distv[r0 + row];
  float2 o;
  o.x = fmaxf(fmaf(sv, w30.x, fmaf(dv, w4v.x, acc.x)), 0.f);
  o.y = fmaxf(fmaf(sv, w30.y, fmaf(dv, w4v.y, acc.y)), 0.f);
  *(float2*)&outmu[(size_t)(r0 + row) * M + cc] = o;
}

// ---------- B-chain epilogue: 2 rows/block; last iter fuses final reduction ----------
__device__ __forceinline__ void epiB_phase(const float* __restrict__ Cp,
                                           const float* __restrict__ W3BT,
                                           const float* __restrict__ biasb,
                                           float* __restrict__ outmu,
                                           int r0, float* smem, int t, bool last,
                                           const float* __restrict__ W7,
                                           float* gsum, unsigned int* gcnt, float* out) {
  float* Cs = smem;   // [2][128]
  {
    int r = t >> 7, m = t & 127;
    float s = 0.f;
#pragma unroll
    for (int kc = 0; kc < 16; kc++) s += Cp[((size_t)kc * N + r0 + r) * M + m];
    Cs[r * 128 + m] = s;
  }
  __syncthreads();
  int row = t >> 7, col = t & 127;
  float acc = 0.f;
#pragma unroll 8
  for (int m = 0; m < 128; m++)
    acc = fmaf(Cs[row * 128 + m], W3BT[m * 128 + col], acc);
  float o = fmaxf(acc + biasb[(size_t)(r0 + row) * M + col], 0.f);
  if (!last) {
    outmu[(size_t)(r0 + row) * M + col] = o;
  } else {
    float part = o * W7[col];
#pragma unroll
    for (int s = 32; s; s >>= 1) part += __shfl_xor(part, s);
    __syncthreads();
    if ((t & 63) == 0) smem[256 + (t >> 6)] = part;
    __syncthreads();
    if (t == 0) {
      float bs = smem[256] + smem[257] + smem[258] + smem[259];
      atomicAdd(gsum, bs);
      __threadfence();
      unsigned int old = atomicAdd(gcnt, 1u);
      if (old == NB - 1) {
        float tot = atomicAdd(gsum, 0.f);
        out[0] = fmaxf(tot, 0.f);
      }
    }
  }
}

// ---------- bias rows (2/block), merged into B-G0 phase ----------
__device__ __forceinline__ void bias_phase(const float* __restrict__ A1f,
                                           const float* __restrict__ A2f,
                                           const float* __restrict__ W4BT,
                                           float* __restrict__ biasb, int r0, int t) {
  int row = t >> 7, col = t & 127;
  const float* a1 = A1f + (size_t)(r0 + row) * M;
  const float* a2 = A2f + (size_t)(r0 + row) * M;
  float acc = 0.f;
#pragma unroll 4
  for (int c = 0; c < 128; c++) acc = fmaf(a1[c], W4BT[c * 128 + col], acc);
#pragma unroll 4
  for (int c = 0; c < 128; c++) acc = fmaf(a2[c], W4BT[(c + 128) * 128 + col], acc);
  biasb[(size_t)(r0 + row) * M + col] = acc;
}

// ================= mega kernel =================
__global__ __launch_bounds__(NT, 2) void mega(KParams P) {
  __shared__ float smem[5248];
  const int t = threadIdx.x;
  const int bid = blockIdx.x;

  // ---- P0: transpose D -> DT; zero final accumulators
  if (bid == 0 && t == 0) { *P.gsum = 0.f; *P.gcnt = 0u; }
  {
    float* tile = smem;
    int tx = t & 31, ty = t >> 5;
#pragma unroll
    for (int rep = 0; rep < 2; rep++) {
      int T = bid + rep * NB;
      int bx = (T & 31) * 32, by = (T >> 5) * 32;
#pragma unroll
      for (int i = 0; i < 4; i++)
        tile[(ty + i * 8) * 33 + tx] = P.D[(size_t)(by + ty + i * 8) * N + bx + tx];
      __syncthreads();
#pragma unroll
      for (int i = 0; i < 4; i++)
        P.DT[(size_t)(bx + ty + i * 8) * N + by + tx] = tile[tx * 33 + ty + i * 8];
      __syncthreads();
    }
  }
  gbar(P.bar, t, bid);

  // ---- P1: weight transposes + edge scores/dual softmax/wd
  {
    int idx = bid * NT + t;
    const float* in = nullptr; float* op = nullptr; int cols = 0, o = 0;
    if (idx < 16512)      { in = P.W3A1; op = P.W3A1T; cols = 129; o = idx; }
    else if (idx < 33024) { in = P.W3A2; op = P.W3A2T; cols = 129; o = idx - 16512; }
    else if (idx < 49408) { in = P.W3B;  op = P.W3BT;  cols = 128; o = idx - 33024; }
    else if (idx < 82176) { in = P.W4B;  op = P.W4BT;  cols = 256; o = idx - 49408; }
    if (in) { int r = o & 127, c = o >> 7; op[o] = in[r * cols + c]; }
  }
  {
    float* red = smem;
    float4* wp = (float4*)(smem + 4);
    if (t < 128) {
      float4 pw;
      pw.x = P.W2[t * 3 + 0]; pw.y = P.W2[t * 3 + 1]; pw.z = P.W2[t * 3 + 2]; pw.w = P.W1[t];
      wp[t] = pw;
    }
    __syncthreads();
    for (int rep = 0; rep < 2; rep++) {
      int v = bid + rep * NB;
      float yv = P.dd[v];
      float x[4], z[4], g[4] = {0.f, 0.f, 0.f, 0.f};
#pragma unroll
      for (int i = 0; i < 4; i++) {
        int u = t + i * 256;
        x[i] = P.DT[(size_t)v * N + u];
        z[i] = P.dd[u];
      }
#pragma unroll 2
      for (int k = 0; k < 128; k++) {
        float4 wk = wp[k];
        float cv = yv * wk.z;
#pragma unroll
        for (int i = 0; i < 4; i++) {
          float h = fmaf(x[i], wk.x, fmaf(z[i], wk.y, cv));
          g[i] = fmaf(fmaxf(h, 0.f), wk.w, g[i]);
        }
      }
#pragma unroll
      for (int i = 0; i < 4; i++)
        if (t + i * 256 == v) g[i] = -INFINITY;
      float m = fmaxf(fmaxf(g[0], g[1]), fmaxf(g[2], g[3]));
      m = blk_max(m, red, t);
      float er[4], es[4], sr = 0.f, ss = 0.f;
#pragma unroll
      for (int i = 0; i < 4; i++) {
        er[i] = expf((g[i] - m) * 0.1f);   // raw /TAU
        es[i] = expf((g[i] - m) * 1e-4f);  // scaled /(1000*TAU)
        sr += er[i]; ss += es[i];
      }
      sr = blk_sum(sr, red, t);
      ss = blk_sum(ss, red, t);
      float ir = 1.f / sr, is = 1.f / ss;
      float a1 = 0.f, a2 = 0.f;
#pragma unroll
      for (int i = 0; i < 4; i++) {
        int u = t + i * 256;
        float pr = er[i] * ir, ps = es[i] * is;
        P.PT2[(size_t)v * N + u] = pr;
        P.PT1[(size_t)v * N + u] = ps;
        a1 += ps * x[i];
        a2 += pr * x[i];
      }
      a1 = blk_sum(a1, red, t);
      a2 = blk_sum(a2, red, t);
      if (t == 0) { P.wd1[v] = a1; P.wd2[v] = a2; }
    }
  }
  gbar(P.bar, t, bid);

  // ---- A chains: 4 iterations, 2 chains concurrent
  {
    const int chain = bid >> 8;
    const int rowblk = (bid >> 3) & 31;
    const int kc = bid & 7;
    const int r0g = rowblk * 32, k0 = kc * 128;
    const float* PT = chain ? P.PT2 : P.PT1;
    float* CpSlot = P.Cp + (size_t)(chain * 8 + kc) * N * M;
    const float* CpChain = P.Cp + (size_t)(chain * 8) * N * M;
    const float* wdv = chain ? P.wd2 : P.wd1;
    const float* distv = chain ? P.ddep : P.dr;
    const float* W3T = chain ? P.W3A2T : P.W3A1T;
    const float* W4c = chain ? P.W4A2 : P.W4A1;
    const float* Wg = chain ? P.W6 : P.W5;
    const int er0 = (bid & 255) * 4;
    const float* cur = chain ? P.mu0A2 : P.mu0A1;
    for (int it = 0; it < 4; it++) {
      gemm_phase(PT, cur, CpSlot, r0g, k0, 128, smem, t);
      gbar(P.bar, t, bid);
      float* nxt = chain ? ((it & 1) ? P.muA2b : P.muA2a)
                         : ((it & 1) ? P.muA1b : P.muA1a);
      epiA_phase(CpChain, cur, wdv, distv, W3T, W4c, Wg, nxt, er0, smem, t);
      gbar(P.bar, t, bid);
      cur = nxt;
    }
  }

  // ---- bias (merged with B-G0) + B chain: 4 iterations
  {
    const int rowblk = bid >> 4, kc = bid & 15;
    const int r0g = rowblk * 32, k0 = kc * 64;
    float* CpSlot = P.Cp + (size_t)kc * N * M;
    const int er0 = bid * 2;
    const float* cur = P.mu0B;
    for (int it = 0; it < 4; it++) {
      if (it == 0) bias_phase(P.muA1b, P.muA2b, P.W4BT, P.biasb, er0, t);
      gemm_phase(P.PT1, cur, CpSlot, r0g, k0, 64, smem, t);
      gbar(P.bar, t, bid);
      float* nxt = (it & 1) ? P.muBb : P.muBa;
      epiB_phase(P.Cp, P.W3BT, P.biasb, nxt, er0, smem, t, it == 3,
                 P.W7, P.gsum, P.gcnt, P.out);
      if (it < 3) gbar(P.bar, t, bid);
      cur = nxt;
    }
  }
}

// ======================================================================
// Fallback path: round-2 multi-kernel pipeline (used if coop launch fails)
// ======================================================================
__global__ __launch_bounds__(256) void k_transpose_d(const float* __restrict__ D,
                                                     float* __restrict__ DT) {
  __shared__ float tile[32][33];
  int tx = threadIdx.x, ty = threadIdx.y;
  int bx = blockIdx.x * 32, by = blockIdx.y * 32;
#pragma unroll
  for (int i = 0; i < 4; i++)
    tile[ty + i * 8][tx] = D[(by + ty + i * 8) * N + bx + tx];
  __syncthreads();
#pragma unroll
  for (int i = 0; i < 4; i++)
    DT[(bx + ty + i * 8) * N + by + tx] = tile[tx][ty + i * 8];
}

__global__ __launch_bounds__(256) void k_prep_w(const float* __restrict__ W3A1, const float* __restrict__ W3A2,
                         const float* __restrict__ W3B, const float* __restrict__ W4B,
                         float* __restrict__ oA1, float* __restrict__ oA2,
                         float* __restrict__ oB, float* __restrict__ o4B) {
  int idx = blockIdx.x * 256 + threadIdx.x;
  const float* in; float* out; int cols; int o;
  if (idx < 16512)      { in = W3A1; out = oA1; cols = 129; o = idx; }
  else if (idx < 33024) { in = W3A2; out = oA2; cols = 129; o = idx - 16512; }
  else if (idx < 49408) { in = W3B;  out = oB;  cols = 128; o = idx - 33024; }
  else if (idx < 82176) { in = W4B;  out = o4B; cols = 256; o = idx - 49408; }
  else return;
  int r = o & 127, c = o >> 7;
  out[o] = in[r * cols + c];
}

__device__ __forceinline__ float blk_max2(float v, float* red, int t) {
#pragma unroll
  for (int o = 32; o; o >>= 1) v = fmaxf(v, __shfl_xor(v, o));
  __syncthreads();
  if ((t & 63) == 0) red[t >> 6] = v;
  __syncthreads();
  return fmaxf(fmaxf(red[0], red[1]), fmaxf(red[2], red[3]));
}
__device__ __forceinline__ float blk_sum2(float v, float* red, int t) {
#pragma unroll
  for (int o = 32; o; o >>= 1) v += __shfl_xor(v, o);
  __syncthreads();
  if ((t & 63) == 0) red[t >> 6] = v;
  __syncthreads();
  return red[0] + red[1] + red[2] + red[3];
}

__global__ __launch_bounds__(256) void k_edge(const float* __restrict__ DT,
                                              const float* __restrict__ dd,
                                              const float* __restrict__ W1,
                                              const float* __restrict__ W2,
                                              float* __restrict__ PT1, float* __restrict__ PT2,
                                              float* __restrict__ wd1, float* __restrict__ wd2) {
  __shared__ float4 wp[128];
  __shared__ float red[4];
  int t = threadIdx.x, v = blockIdx.x;
  if (t < 128) {
    float4 p;
    p.x = W2[t * 3 + 0]; p.y = W2[t * 3 + 1]; p.z = W2[t * 3 + 2]; p.w = W1[t];
    wp[t] = p;
  }
  __syncthreads();
  float yv = dd[v];
  float x[4], z[4], g[4] = {0.f, 0.f, 0.f, 0.f};
#pragma unroll
  for (int i = 0; i < 4; i++) {
    int u = t + i * 256;
    x[i] = DT[v * N + u];
    z[i] = dd[u];
  }
#pragma unroll 2
  for (int k = 0; k < 128; k++) {
    float4 wk = wp[k];
    float cv = yv * wk.z;
#pragma unroll
    for (int i = 0; i < 4; i++) {
      float h = fmaf(x[i], wk.x, fmaf(z[i], wk.y, cv));
      g[i] = fmaf(fmaxf(h, 0.f), wk.w, g[i]);
    }
  }
#pragma unroll
  for (int i = 0; i < 4; i++)
    if (t + i * 256 == v) g[i] = -INFINITY;
  float m = fmaxf(fmaxf(g[0], g[1]), fmaxf(g[2], g[3]));
  m = blk_max2(m, red, t);
  float er[4], es[4], sr = 0.f, ss = 0.f;
#pragma unroll
  for (int i = 0; i < 4; i++) {
    er[i] = expf((g[i] - m) * 0.1f);
    es[i] = expf((g[i] - m) * 1e-4f);
    sr += er[i]; ss += es[i];
  }
  sr = blk_sum2(sr, red, t);
  ss = blk_sum2(ss, red, t);
  float ir = 1.f / sr, is = 1.f / ss;
  float a1 = 0.f, a2 = 0.f;
#pragma unroll
  for (int i = 0; i < 4; i++) {
    int u = t + i * 256;
    float pr = er[i] * ir, ps = es[i] * is;
    PT2[v * N + u] = pr;
    PT1[v * N + u] = ps;
    a1 += ps * x[i];
    a2 += pr * x[i];
  }
  a1 = blk_sum2(a1, red, t);
  a2 = blk_sum2(a2, red, t);
  if (t == 0) { wd1[v] = a1; wd2[v] = a2; }
}

__global__ __launch_bounds__(256) void k_gemm(const float* __restrict__ PT0, const float* __restrict__ mu_0, float* __restrict__ C_0,
                                              const float* __restrict__ PT1p, const float* __restrict__ mu_1, float* __restrict__ C_1) {
  int z = blockIdx.z;
  const float* PT = z ? PT1p : PT0;
  const float* mu = z ? mu_1 : mu_0;
  float* C = z ? C_1 : C_0;
  __shared__ float As[32][18];
  __shared__ float Bs[32][128];
  int t = threadIdx.x;
  int r0 = blockIdx.x * 16, k0 = blockIdx.y * 256;
  int tr = t >> 5, tc = t & 31;
  int lr = t >> 4, lk = t & 15;
  float4 acc0 = {0, 0, 0, 0}, acc1 = {0, 0, 0, 0};
  for (int kt = 0; kt < 256; kt += 32) {
    const float* psrc = &PT[(r0 + lr) * N + k0 + kt + lk];
    float a0 = psrc[0], a1 = psrc[16];
#pragma unroll
    for (int i = 0; i < 4; i++) {
      int e = t + i * 256, br = e >> 5, bc = e & 31;
      *(float4*)&Bs[br][bc * 4] = *(const float4*)&mu[(k0 + kt + br) * M + bc * 4];
    }
    As[lk][lr] = a0;
    As[lk + 16][lr] = a1;
    __syncthreads();
#pragma unroll
    for (int kk = 0; kk < 32; kk++) {
      float2 av = *(const float2*)&As[kk][tr * 2];
      float4 b = *(const float4*)&Bs[kk][tc * 4];
      acc0.x = fmaf(av.x, b.x, acc0.x); acc0.y = fmaf(av.x, b.y, acc0.y);
      acc0.z = fmaf(av.x, b.z, acc0.z); acc0.w = fmaf(av.x, b.w, acc0.w);
      acc1.x = fmaf(av.y, b.x, acc1.x); acc1.y = fmaf(av.y, b.y, acc1.y);
      acc1.z = fmaf(av.y, b.z, acc1.z); acc1.w = fmaf(av.y, b.w, acc1.w);
    }
    __syncthreads();
  }
  float* dst = C + ((size_t)blockIdx.y * N + r0 + tr * 2) * M + tc * 4;
  *(float4*)dst = acc0;
  *(float4*)(dst + M) = acc1;
}

__global__ __launch_bounds__(256) void k_epi(int modeA,
    const float* __restrict__ Cp_0, const float* __restrict__ muold_0,
    const float* __restrict__ wd_0, const float* __restrict__ dist_0,
    const float* __restrict__ W3T_0, const float* __restrict__ W4c_0,
    const float* __restrict__ Wg_0, float* __restrict__ out_0,
    const float* __restrict__ Cp_1, const float* __restrict__ muold_1,
    const float* __restrict__ wd_1, const float* __restrict__ dist_1,
    const float* __restrict__ W3T_1, const float* __restrict__ W4c_1,
    const float* __restrict__ Wg_1, float* __restrict__ out_1,
    const float* __restrict__ bias) {
  int z = blockIdx.z;
  const float* Cp = z ? Cp_1 : Cp_0;
  const float* muold = z ? muold_1 : muold_0;
  const float* wd = z ? wd_1 : wd_0;
  const float* dist = z ? dist_1 : dist_0;
  const float* W3T = z ? W3T_1 : W3T_0;
  const float* W4c = z ? W4c_1 : W4c_0;
  const float* Wg = z ? Wg_1 : Wg_0;
  float* out = z ? out_1 : out_0;
  __shared__ float Cs[8][129];
  __shared__ float swd[8];
  int t = threadIdx.x, r0 = blockIdx.x * 8;
#pragma unroll
  for (int i = 0; i < 4; i++) {
    int e = t + i * 256, r = e >> 7, m = e & 127;
    float s = 0.f;
#pragma unroll
    for (int c = 0; c < 4; c++) s += Cp[((size_t)c * N + r0 + r) * M + m];
    Cs[r][m] = s;
  }
  if (modeA) {
    int row = t >> 5, g = t & 31;
    const float* mo = muold + (r0 + row) * M + g * 4;
    float sp = 0.f;
#pragma unroll
    for (int j = 0; j < 4; j++) sp = fmaf(mo[j], Wg[g * 4 + j], sp);
#pragma unroll
    for (int o = 16; o; o >>= 1) sp += __shfl_xor(sp, o);
    if (g == 0) swd[row] = wd[r0 + row] * fmaxf(sp, 0.f);
  }
  __syncthreads();
  int tr = t >> 5, tc = t & 31;
  float4 acc = {0, 0, 0, 0};
  int off = modeA ? 1 : 0;
#pragma unroll 8
  for (int m = 0; m < 128; m++) {
    float a = Cs[tr][m];
    float4 wv = *(const float4*)&W3T[(m + off) * 128 + tc * 4];
    acc.x = fmaf(a, wv.x, acc.x); acc.y = fmaf(a, wv.y, acc.y);
    acc.z = fmaf(a, wv.z, acc.z); acc.w = fmaf(a, wv.w, acc.w);
  }
  int ra = r0 + tr;
  float4 e0;
  if (modeA) {
    float4 w30 = *(const float4*)&W3T[tc * 4];
    float4 w4v = *(const float4*)&W4c[tc * 4];
    float s0 = swd[tr];
    float d0 = dist[ra];
    e0.x = s0 * w30.x + d0 * w4v.x; e0.y = s0 * w30.y + d0 * w4v.y;
    e0.z = s0 * w30.z + d0 * w4v.z; e0.w = s0 * w30.w + d0 * w4v.w;
  } else {
    e0 = *(const float4*)&bias[ra * M + tc * 4];
  }
  float4 o0;
  o0.x = fmaxf(acc.x + e0.x, 0.f); o0.y = fmaxf(acc.y + e0.y, 0.f);
  o0.z = fmaxf(acc.z + e0.z, 0.f); o0.w = fmaxf(acc.w + e0.w, 0.f);
  *(float4*)&out[ra * M + tc * 4] = o0;
}

__global__ __launch_bounds__(256) void k_bias(const float* __restrict__ A1,
                                              const float* __restrict__ A2,
                                              const float* __restrict__ W4BT,
                                              float* __restrict__ bias) {
  __shared__ float Cs[16][257];
  int t = threadIdx.x, r0 = blockIdx.x * 16;
#pragma unroll
  for (int i = 0; i < 16; i++) {
    int e = t + i * 256, r = e >> 8, c = e & 255;
    Cs[r][c] = (c < 128) ? A1[(r0 + r) * M + c] : A2[(r0 + r) * M + (c - 128)];
  }
  __syncthreads();
  int tr = t >> 5, tc = t & 31;
  float4 acc0 = {0, 0, 0, 0}, acc1 = {0, 0, 0, 0};
#pragma unroll 4
  for (int m = 0; m < 256; m++) {
    float a0 = Cs[tr * 2][m], a1 = Cs[tr * 2 + 1][m];
    float4 wv = *(const float4*)&W4BT[m * 128 + tc * 4];
    acc0.x = fmaf(a0, wv.x, acc0.x); acc0.y = fmaf(a0, wv.y, acc0.y);
    acc0.z = fmaf(a0, wv.z, acc0.z); acc0.w = fmaf(a0, wv.w, acc0.w);
    acc1.x = fmaf(a1, wv.x, acc1.x); acc1.y = fmaf(a1, wv.y, acc1.y);
    acc1.z = fmaf(a1, wv.z, acc1.z); acc1.w = fmaf(a1, wv.w, acc1.w);
  }
  int ra = r0 + tr * 2, rb = ra + 1;
  *(float4*)&bias[ra * M + tc * 4] = acc0;
  *(float4*)&bias[rb * M + tc * 4] = acc1;
}

__global__ __launch_bounds__(1024) void k_final(const float* __restrict__ mu,
                                                const float* __restrict__ W7,
                                                float* __restrict__ out) {
  __shared__ float red[1024];
  int t = threadIdx.x;
  int j = t & 127, q = t >> 7;
  float acc = 0.f;
  for (int v = q; v < N; v += 8) acc += mu[v * M + j];
  red[t] = acc;
  __syncthreads();
  float tot = 0.f;
  if (t < 128) {
    float cs = 0.f;
#pragma unroll
    for (int s = 0; s < 8; s++) cs += red[s * 128 + t];
    tot = cs * W7[t];
#pragma unroll
    for (int o = 32; o; o >>= 1) tot += __shfl_xor(tot, o);
  }
  __syncthreads();
  if (t == 0) red[0] = tot;
  if (t == 64) red[1] = tot;
  __syncthreads();
  if (t == 0) out[0] = fmaxf(red[0] + red[1], 0.f);
}

extern "C" void kernel_launch(void* const* d_in, const int* in_sizes, int n_in,
                              void* d_out, int out_size, void* d_ws, size_t ws_size,
                              hipStream_t stream) {
  (void)in_sizes; (void)n_in; (void)out_size; (void)ws_size;
  const float* D     = (const float*)d_in[0];
  const float* dd    = (const float*)d_in[1];
  const float* dr    = (const float*)d_in[2];
  const float* ddep  = (const float*)d_in[3];
  const float* mu0A1 = (const float*)d_in[4];
  const float* mu0A2 = (const float*)d_in[5];
  const float* mu0B  = (const float*)d_in[6];
  const float* W1    = (const float*)d_in[7];
  const float* W2    = (const float*)d_in[8];
  const float* W3A1  = (const float*)d_in[9];
  const float* W3A2  = (const float*)d_in[10];
  const float* W4A1  = (const float*)d_in[11];
  const float* W4A2  = (const float*)d_in[12];
  const float* W3B   = (const float*)d_in[13];
  const float* W4B   = (const float*)d_in[14];
  const float* W5    = (const float*)d_in[15];
  const float* W6    = (const float*)d_in[16];
  const float* W7    = (const float*)d_in[17];

  float* w = (float*)d_ws;
  size_t o = 0;
  auto alloc = [&](size_t n) { float* p = w + o; o += n; return p; };
  float* Cp    = alloc((size_t)16 * N * M);     // 8 MB partials
  float* DT    = alloc((size_t)N * N);
  float* PT1   = alloc((size_t)N * N);
  float* PT2   = alloc((size_t)N * N);
  float* wd1   = alloc(N);
  float* wd2   = alloc(N);
  float* W3A1T = alloc(129 * 128);
  float* W3A2T = alloc(129 * 128);
  float* W3BT  = alloc(128 * 128);
  float* W4BT  = alloc(256 * 128);
  float* muA1a = alloc((size_t)N * M); float* muA1b = alloc((size_t)N * M);
  float* muA2a = alloc((size_t)N * M); float* muA2b = alloc((size_t)N * M);
  float* muBa  = alloc((size_t)N * M); float* muBb  = alloc((size_t)N * M);
  float* biasb = alloc((size_t)N * M);
  float* sync_base = alloc(0);
  float* gsum  = alloc(1);
  unsigned int* gcnt = (unsigned int*)alloc(1);
  alloc(14);  // pad so bar starts 64B-aligned
  unsigned int* bar = (unsigned int*)alloc(160);

  KParams p;
  p.D = D; p.dd = dd; p.dr = dr; p.ddep = ddep;
  p.mu0A1 = mu0A1; p.mu0A2 = mu0A2; p.mu0B = mu0B;
  p.W1 = W1; p.W2 = W2; p.W3A1 = W3A1; p.W3A2 = W3A2;
  p.W4A1 = W4A1; p.W4A2 = W4A2; p.W3B = W3B; p.W4B = W4B;
  p.W5 = W5; p.W6 = W6; p.W7 = W7;
  p.DT = DT; p.PT1 = PT1; p.PT2 = PT2; p.wd1 = wd1; p.wd2 = wd2;
  p.W3A1T = W3A1T; p.W3A2T = W3A2T; p.W3BT = W3BT; p.W4BT = W4BT;
  p.muA1a = muA1a; p.muA1b = muA1b; p.muA2a = muA2a; p.muA2b = muA2b;
  p.muBa = muBa; p.muBb = muBb; p.biasb = biasb;
  p.Cp = Cp; p.gsum = gsum; p.gcnt = gcnt; p.bar = bar; p.out = (float*)d_out;

  // un-poison barrier/accumulator state each call (graph-capturable memset node)
  hipMemsetAsync((void*)sync_base, 0, (size_t)(2 + 14 + 160) * sizeof(float), stream);

  void* args[] = { (void*)&p };
  hipError_t err = hipLaunchCooperativeKernel((const void*)mega, dim3(NB), dim3(NT),
                                              args, 0, stream);
  if (err == hipSuccess) return;

  // ---------- fallback: multi-kernel pipeline ----------
  k_transpose_d<<<dim3(32, 32), dim3(32, 8), 0, stream>>>(D, DT);
  k_prep_w<<<321, 256, 0, stream>>>(W3A1, W3A2, W3B, W4B, W3A1T, W3A2T, W3BT, W4BT);
  k_edge<<<N, 256, 0, stream>>>(DT, dd, W1, W2, PT1, PT2, wd1, wd2);
  float* Cp0 = Cp;
  float* Cp1 = Cp + 4 * N * M;
  const float* cur1 = mu0A1;
  const float* cur2 = mu0A2;
  float* b1[2] = {muA1a, muA1b};
  float* b2[2] = {muA2a, muA2b};
  for (int t = 0; t < 4; t++) {
    k_gemm<<<dim3(64, 4, 2), 256, 0, stream>>>(PT1, cur1, Cp0, PT2, cur2, Cp1);
    k_epi<<<dim3(128, 1, 2), 256, 0, stream>>>(1,
        Cp0, cur1, wd1, dr,   W3A1T, W4A1, W5, b1[t & 1],
        Cp1, cur2, wd2, ddep, W3A2T, W4A2, W6, b2[t & 1], (const float*)nullptr);
    cur1 = b1[t & 1];
    cur2 = b2[t & 1];
  }
  k_bias<<<64, 256, 0, stream>>>(cur1, cur2, W4BT, biasb);
  const float* curB = mu0B;
  float* bB[2] = {muBa, muBb};
  for (int t = 0; t < 4; t++) {
    k_gemm<<<dim3(64, 4, 1), 256, 0, stream>>>(PT1, curB, Cp0, PT1, curB, Cp0);
    k_epi<<<dim3(128, 1, 1), 256, 0, stream>>>(0,
        Cp0, (const float*)nullptr, (const float*)nullptr, (const float*)nullptr,
        W3BT, (const float*)nullptr, (const float*)nullptr, bB[t & 1],
        (const float*)nullptr, (const float*)nullptr, (const float*)nullptr, (const float*)nullptr,
        (const float*)nullptr, (const float*)nullptr, (const float*)nullptr, (float*)nullptr,
        biasb);
    curB = bB[t & 1];
  }
  k_final<<<1, 1024, 0, stream>>>(curB, W7, (float*)d_out);
}

// Round 5
// 430.183 us; speedup vs baseline: 2.7321x; 1.7176x over previous
//
#include <hip/hip_runtime.h>
#include <math.h>

#define N 1024
#define M 128

// ---------------- prep: transpose D, transpose weights, zero accumulators ----------------
__global__ __launch_bounds__(256) void k_prep(const float* __restrict__ D, float* __restrict__ DT,
    const float* __restrict__ W3A1, const float* __restrict__ W3A2,
    const float* __restrict__ W3B, const float* __restrict__ W4B,
    float* __restrict__ oA1, float* __restrict__ oA2,
    float* __restrict__ oB, float* __restrict__ o4B,
    float* __restrict__ gsum, unsigned int* __restrict__ gcnt) {
  int bx = blockIdx.x, t = threadIdx.x;
  if (bx < 1024) {
    __shared__ float tile[32 * 33];
    int tx = t & 31, ty = t >> 5;
    int bxx = (bx & 31) * 32, by = (bx >> 5) * 32;
#pragma unroll
    for (int i = 0; i < 4; i++)
      tile[(ty + i * 8) * 33 + tx] = D[(size_t)(by + ty + i * 8) * N + bxx + tx];
    __syncthreads();
#pragma unroll
    for (int i = 0; i < 4; i++)
      DT[(size_t)(bxx + ty + i * 8) * N + by + tx] = tile[tx * 33 + ty + i * 8];
  } else if (bx < 1345) {
    int idx = (bx - 1024) * 256 + t;
    const float* in = nullptr; float* op = nullptr; int cols = 0, o = 0;
    if (idx < 16512)      { in = W3A1; op = oA1; cols = 129; o = idx; }
    else if (idx < 33024) { in = W3A2; op = oA2; cols = 129; o = idx - 16512; }
    else if (idx < 49408) { in = W3B;  op = oB;  cols = 128; o = idx - 33024; }
    else if (idx < 82176) { in = W4B;  op = o4B; cols = 256; o = idx - 49408; }
    if (in) { int r = o & 127, c = o >> 7; op[o] = in[r * cols + c]; }
  } else {
    if (t == 0) { *gsum = 0.f; *gcnt = 0u; }
  }
}

// ---------------- block reductions ----------------
__device__ __forceinline__ float blk_max(float v, float* red, int t) {
#pragma unroll
  for (int o = 32; o; o >>= 1) v = fmaxf(v, __shfl_xor(v, o));
  __syncthreads();
  if ((t & 63) == 0) red[t >> 6] = v;
  __syncthreads();
  return fmaxf(fmaxf(red[0], red[1]), fmaxf(red[2], red[3]));
}
__device__ __forceinline__ float blk_sum(float v, float* red, int t) {
#pragma unroll
  for (int o = 32; o; o >>= 1) v += __shfl_xor(v, o);
  __syncthreads();
  if ((t & 63) == 0) red[t >> 6] = v;
  __syncthreads();
  return red[0] + red[1] + red[2] + red[3];
}

// ---------------- edge scores + dual softmax + wd ----------------
// G_scaled = G_raw/1000 exactly (relu positively homogeneous) -> one MLP pass, two temps.
__global__ __launch_bounds__(256) void k_edge(const float* __restrict__ DT,
                                              const float* __restrict__ dd,
                                              const float* __restrict__ W1,
                                              const float* __restrict__ W2,
                                              float* __restrict__ PT1, float* __restrict__ PT2,
                                              float* __restrict__ wd1, float* __restrict__ wd2) {
  __shared__ float4 wp[128];
  __shared__ float red[4];
  int t = threadIdx.x, v = blockIdx.x;
  if (t < 128) {
    float4 p;
    p.x = W2[t * 3 + 0]; p.y = W2[t * 3 + 1]; p.z = W2[t * 3 + 2]; p.w = W1[t];
    wp[t] = p;
  }
  __syncthreads();
  float yv = dd[v];
  float x[4], z[4], g[4] = {0.f, 0.f, 0.f, 0.f};
#pragma unroll
  for (int i = 0; i < 4; i++) {
    int u = t + i * 256;
    x[i] = DT[(size_t)v * N + u];
    z[i] = dd[u];
  }
#pragma unroll 2
  for (int k = 0; k < 128; k++) {
    float4 wk = wp[k];
    float cv = yv * wk.z;
#pragma unroll
    for (int i = 0; i < 4; i++) {
      float h = fmaf(x[i], wk.x, fmaf(z[i], wk.y, cv));
      g[i] = fmaf(fmaxf(h, 0.f), wk.w, g[i]);
    }
  }
#pragma unroll
  for (int i = 0; i < 4; i++)
    if (t + i * 256 == v) g[i] = -INFINITY;
  float m = fmaxf(fmaxf(g[0], g[1]), fmaxf(g[2], g[3]));
  m = blk_max(m, red, t);
  float er[4], es[4], sr = 0.f, ss = 0.f;
#pragma unroll
  for (int i = 0; i < 4; i++) {
    er[i] = expf((g[i] - m) * 0.1f);     // raw: /TAU
    es[i] = expf((g[i] - m) * 1e-4f);    // scaled: /(1000*TAU)
    sr += er[i]; ss += es[i];
  }
  sr = blk_sum(sr, red, t);
  ss = blk_sum(ss, red, t);
  float ir = 1.f / sr, is = 1.f / ss;
  float a1 = 0.f, a2 = 0.f;
#pragma unroll
  for (int i = 0; i < 4; i++) {
    int u = t + i * 256;
    float pr = er[i] * ir, ps = es[i] * is;
    PT2[(size_t)v * N + u] = pr;
    PT1[(size_t)v * N + u] = ps;
    a1 += ps * x[i];
    a2 += pr * x[i];
  }
  a1 = blk_sum(a1, red, t);
  a2 = blk_sum(a2, red, t);
  if (t == 0) { wd1[v] = a1; wd2[v] = a2; }
}

// ---------------- GEMM core: 16 rows x 128 cols, full K=1024 (no split-K) ----------------
// smem layout: As = smem[0..576) k-major [32][18]; Bs = smem[576..4672) [32][128]
// after k-loop, smem reused: Cs [16][129] + swd[16]
__device__ __forceinline__ void gemm16(const float* __restrict__ PT,
                                       const float* __restrict__ cur,
                                       float* smem, int r0, int t,
                                       float4& a0, float4& a1) {
  float* As = smem;
  float* Bs = smem + 576;
  const int tr = t >> 5;         // 0..7 (2 rows each)
  const int tc = t & 31;         // col group *4
  const int lr = t >> 4;         // staging row 0..15
  const int kb = (t & 15) * 2;   // staging k pair
  a0 = {0, 0, 0, 0}; a1 = {0, 0, 0, 0};
  for (int k0 = 0; k0 < N; k0 += 32) {
    float2 av2 = *(const float2*)&PT[(size_t)(r0 + lr) * N + k0 + kb];
#pragma unroll
    for (int i = 0; i < 4; i++) {
      int e = t + i * 256, br = e >> 5, bc = (e & 31) * 4;
      *(float4*)&Bs[br * 128 + bc] = *(const float4*)&cur[(size_t)(k0 + br) * M + bc];
    }
    As[(kb + 0) * 18 + lr] = av2.x;
    As[(kb + 1) * 18 + lr] = av2.y;
    __syncthreads();
#pragma unroll
    for (int kk = 0; kk < 32; kk++) {
      float2 av = *(const float2*)&As[kk * 18 + tr * 2];
      float4 bv = *(const float4*)&Bs[kk * 128 + tc * 4];
      a0.x = fmaf(av.x, bv.x, a0.x); a0.y = fmaf(av.x, bv.y, a0.y);
      a0.z = fmaf(av.x, bv.z, a0.z); a0.w = fmaf(av.x, bv.w, a0.w);
      a1.x = fmaf(av.y, bv.x, a1.x); a1.y = fmaf(av.y, bv.y, a1.y);
      a1.z = fmaf(av.y, bv.z, a1.z); a1.w = fmaf(av.y, bv.w, a1.w);
    }
    __syncthreads();
  }
  // stash C into LDS (reuse As/Bs space): Cs[16][129]
  float* Cs = smem;
  int rA = tr * 2, rB = rA + 1, c0 = tc * 4;
  Cs[rA * 129 + c0 + 0] = a0.x; Cs[rA * 129 + c0 + 1] = a0.y;
  Cs[rA * 129 + c0 + 2] = a0.z; Cs[rA * 129 + c0 + 3] = a0.w;
  Cs[rB * 129 + c0 + 0] = a1.x; Cs[rB * 129 + c0 + 1] = a1.y;
  Cs[rB * 129 + c0 + 2] = a1.z; Cs[rB * 129 + c0 + 3] = a1.w;
  __syncthreads();
}

// ---------------- fused A-iteration: gemm + layer epilogue ----------------
__global__ __launch_bounds__(256) void k_iterA(
    const float* __restrict__ PT1, const float* __restrict__ PT2,
    const float* __restrict__ cur1, const float* __restrict__ cur2,
    float* __restrict__ nxt1, float* __restrict__ nxt2,
    const float* __restrict__ wd1, const float* __restrict__ wd2,
    const float* __restrict__ dr, const float* __restrict__ ddep,
    const float* __restrict__ W3A1T, const float* __restrict__ W3A2T,
    const float* __restrict__ W4A1, const float* __restrict__ W4A2,
    const float* __restrict__ W5, const float* __restrict__ W6) {
  __shared__ float smem[4672 + 16];
  int z = blockIdx.z;
  const float* PT = z ? PT2 : PT1;
  const float* cur = z ? cur2 : cur1;
  float* nxt = z ? nxt2 : nxt1;
  const float* wdv = z ? wd2 : wd1;
  const float* dist = z ? ddep : dr;
  const float* W3T = z ? W3A2T : W3A1T;
  const float* W4c = z ? W4A2 : W4A1;
  const float* Wg = z ? W6 : W5;
  int t = threadIdx.x, r0 = blockIdx.x * 16;

  float4 a0, a1;
  gemm16(PT, cur, smem, r0, t, a0, a1);
  float* Cs = smem;
  float* swd = smem + 4672;

  // swd[row] = wd[row] * relu(muold_row . Wg)
  {
    int row = t >> 4, l = t & 15;
    const float* mo = cur + (size_t)(r0 + row) * M + l * 8;
    const float* wg = Wg + l * 8;
    float sp = 0.f;
#pragma unroll
    for (int j = 0; j < 8; j++) sp = fmaf(mo[j], wg[j], sp);
#pragma unroll
    for (int o = 8; o; o >>= 1) sp += __shfl_xor(sp, o);
    if (l == 0) swd[row] = wdv[r0 + row] * fmaxf(sp, 0.f);
  }
  __syncthreads();

  // out_row = relu(Cs_row @ W3T[1:,:] + swd*W3T[0,:] + dist*W4c)
  int row = t >> 4, c8 = (t & 15) * 8;
  float acc[8] = {0, 0, 0, 0, 0, 0, 0, 0};
#pragma unroll 4
  for (int m = 0; m < 128; m++) {
    float a = Cs[row * 129 + m];
    float4 w0 = *(const float4*)&W3T[(m + 1) * 128 + c8];
    float4 w1 = *(const float4*)&W3T[(m + 1) * 128 + c8 + 4];
    acc[0] = fmaf(a, w0.x, acc[0]); acc[1] = fmaf(a, w0.y, acc[1]);
    acc[2] = fmaf(a, w0.z, acc[2]); acc[3] = fmaf(a, w0.w, acc[3]);
    acc[4] = fmaf(a, w1.x, acc[4]); acc[5] = fmaf(a, w1.y, acc[5]);
    acc[6] = fmaf(a, w1.z, acc[6]); acc[7] = fmaf(a, w1.w, acc[7]);
  }
  float4 w30a = *(const float4*)&W3T[c8];
  float4 w30b = *(const float4*)&W3T[c8 + 4];
  float4 w4a = *(const float4*)&W4c[c8];
  float4 w4b = *(const float4*)&W4c[c8 + 4];
  float sv = swd[row], dv = dist[r0 + row];
  float4 o0, o1;
  o0.x = fmaxf(fmaf(sv, w30a.x, fmaf(dv, w4a.x, acc[0])), 0.f);
  o0.y = fmaxf(fmaf(sv, w30a.y, fmaf(dv, w4a.y, acc[1])), 0.f);
  o0.z = fmaxf(fmaf(sv, w30a.z, fmaf(dv, w4a.z, acc[2])), 0.f);
  o0.w = fmaxf(fmaf(sv, w30a.w, fmaf(dv, w4a.w, acc[3])), 0.f);
  o1.x = fmaxf(fmaf(sv, w30b.x, fmaf(dv, w4b.x, acc[4])), 0.f);
  o1.y = fmaxf(fmaf(sv, w30b.y, fmaf(dv, w4b.y, acc[5])), 0.f);
  o1.z = fmaxf(fmaf(sv, w30b.z, fmaf(dv, w4b.z, acc[6])), 0.f);
  o1.w = fmaxf(fmaf(sv, w30b.w, fmaf(dv, w4b.w, acc[7])), 0.f);
  float* dst = nxt + (size_t)(r0 + row) * M + c8;
  *(float4*)dst = o0;
  *(float4*)(dst + 4) = o1;
}

// ---------------- fused B-iteration: gemm + bias(iter0) + epilogue + final(iter3) ----------------
__global__ __launch_bounds__(256) void k_iterB(
    const float* __restrict__ PT1, const float* __restrict__ cur, float* __restrict__ nxt,
    const float* __restrict__ W3BT, const float* __restrict__ W4BT, float* __restrict__ biasb,
    const float* __restrict__ A1f, const float* __restrict__ A2f,
    const float* __restrict__ W7, float* __restrict__ gsum, unsigned int* __restrict__ gcnt,
    float* __restrict__ out, int flags) {
  __shared__ float smem[4672];
  __shared__ float red[4];
  int t = threadIdx.x, r0 = blockIdx.x * 16;

  float4 a0, a1;
  gemm16(PT1, cur, smem, r0, t, a0, a1);
  float* Cs = smem;

  int row = t >> 4, c8 = (t & 15) * 8;
  // bias rows: iter0 computes + stores, later iters load
  float bv[8];
  if (flags & 1) {
#pragma unroll
    for (int j = 0; j < 8; j++) bv[j] = 0.f;
    const float* a1r = A1f + (size_t)(r0 + row) * M;
    const float* a2r = A2f + (size_t)(r0 + row) * M;
#pragma unroll 4
    for (int c = 0; c < 128; c++) {
      float a = a1r[c];
      float4 w0 = *(const float4*)&W4BT[c * 128 + c8];
      float4 w1 = *(const float4*)&W4BT[c * 128 + c8 + 4];
      bv[0] = fmaf(a, w0.x, bv[0]); bv[1] = fmaf(a, w0.y, bv[1]);
      bv[2] = fmaf(a, w0.z, bv[2]); bv[3] = fmaf(a, w0.w, bv[3]);
      bv[4] = fmaf(a, w1.x, bv[4]); bv[5] = fmaf(a, w1.y, bv[5]);
      bv[6] = fmaf(a, w1.z, bv[6]); bv[7] = fmaf(a, w1.w, bv[7]);
    }
#pragma unroll 4
    for (int c = 0; c < 128; c++) {
      float a = a2r[c];
      float4 w0 = *(const float4*)&W4BT[(c + 128) * 128 + c8];
      float4 w1 = *(const float4*)&W4BT[(c + 128) * 128 + c8 + 4];
      bv[0] = fmaf(a, w0.x, bv[0]); bv[1] = fmaf(a, w0.y, bv[1]);
      bv[2] = fmaf(a, w0.z, bv[2]); bv[3] = fmaf(a, w0.w, bv[3]);
      bv[4] = fmaf(a, w1.x, bv[4]); bv[5] = fmaf(a, w1.y, bv[5]);
      bv[6] = fmaf(a, w1.z, bv[6]); bv[7] = fmaf(a, w1.w, bv[7]);
    }
    float* bdst = biasb + (size_t)(r0 + row) * M + c8;
    *(float4*)bdst = {bv[0], bv[1], bv[2], bv[3]};
    *(float4*)(bdst + 4) = {bv[4], bv[5], bv[6], bv[7]};
  } else {
    const float* bsrc = biasb + (size_t)(r0 + row) * M + c8;
    float4 b0 = *(const float4*)bsrc;
    float4 b1 = *(const float4*)(bsrc + 4);
    bv[0] = b0.x; bv[1] = b0.y; bv[2] = b0.z; bv[3] = b0.w;
    bv[4] = b1.x; bv[5] = b1.y; bv[6] = b1.z; bv[7] = b1.w;
  }

  float acc[8] = {0, 0, 0, 0, 0, 0, 0, 0};
#pragma unroll 4
  for (int m = 0; m < 128; m++) {
    float a = Cs[row * 129 + m];
    float4 w0 = *(const float4*)&W3BT[m * 128 + c8];
    float4 w1 = *(const float4*)&W3BT[m * 128 + c8 + 4];
    acc[0] = fmaf(a, w0.x, acc[0]); acc[1] = fmaf(a, w0.y, acc[1]);
    acc[2] = fmaf(a, w0.z, acc[2]); acc[3] = fmaf(a, w0.w, acc[3]);
    acc[4] = fmaf(a, w1.x, acc[4]); acc[5] = fmaf(a, w1.y, acc[5]);
    acc[6] = fmaf(a, w1.z, acc[6]); acc[7] = fmaf(a, w1.w, acc[7]);
  }
  float o[8];
#pragma unroll
  for (int j = 0; j < 8; j++) o[j] = fmaxf(acc[j] + bv[j], 0.f);

  if (!(flags & 2)) {
    float* dst = nxt + (size_t)(r0 + row) * M + c8;
    *(float4*)dst = {o[0], o[1], o[2], o[3]};
    *(float4*)(dst + 4) = {o[4], o[5], o[6], o[7]};
  } else {
    // final: relu(W7 . colsum(mu)) via cross-block atomic reduce
    float s = 0.f;
#pragma unroll
    for (int j = 0; j < 8; j++) s = fmaf(o[j], W7[c8 + j], s);
#pragma unroll
    for (int off = 32; off; off >>= 1) s += __shfl_xor(s, off);
    if ((t & 63) == 0) red[t >> 6] = s;
    __syncthreads();
    if (t == 0) {
      float bs = red[0] + red[1] + red[2] + red[3];
      atomicAdd(gsum, bs);
      __threadfence();
      unsigned int old = atomicAdd(gcnt, 1u);
      if (old == 63u) {
        float tot = atomicAdd(gsum, 0.f);
        out[0] = fmaxf(tot, 0.f);
      }
    }
  }
}

extern "C" void kernel_launch(void* const* d_in, const int* in_sizes, int n_in,
                              void* d_out, int out_size, void* d_ws, size_t ws_size,
                              hipStream_t stream) {
  (void)in_sizes; (void)n_in; (void)out_size; (void)ws_size;
  const float* D     = (const float*)d_in[0];
  const float* dd    = (const float*)d_in[1];
  const float* dr    = (const float*)d_in[2];
  const float* ddep  = (const float*)d_in[3];
  const float* mu0A1 = (const float*)d_in[4];
  const float* mu0A2 = (const float*)d_in[5];
  const float* mu0B  = (const float*)d_in[6];
  const float* W1    = (const float*)d_in[7];
  const float* W2    = (const float*)d_in[8];
  const float* W3A1  = (const float*)d_in[9];
  const float* W3A2  = (const float*)d_in[10];
  const float* W4A1  = (const float*)d_in[11];
  const float* W4A2  = (const float*)d_in[12];
  const float* W3B   = (const float*)d_in[13];
  const float* W4B   = (const float*)d_in[14];
  const float* W5    = (const float*)d_in[15];
  const float* W6    = (const float*)d_in[16];
  const float* W7    = (const float*)d_in[17];

  float* w = (float*)d_ws;
  size_t o = 0;
  auto alloc = [&](size_t n) { float* p = w + o; o += n; return p; };
  float* DT    = alloc((size_t)N * N);
  float* PT1   = alloc((size_t)N * N);
  float* PT2   = alloc((size_t)N * N);
  float* wd1   = alloc(N);
  float* wd2   = alloc(N);
  float* W3A1T = alloc(129 * 128);
  float* W3A2T = alloc(129 * 128);
  float* W3BT  = alloc(128 * 128);
  float* W4BT  = alloc(256 * 128);
  float* muA1a = alloc((size_t)N * M); float* muA1b = alloc((size_t)N * M);
  float* muA2a = alloc((size_t)N * M); float* muA2b = alloc((size_t)N * M);
  float* muBa  = alloc((size_t)N * M); float* muBb  = alloc((size_t)N * M);
  float* biasb = alloc((size_t)N * M);
  float* gsum  = alloc(1);
  unsigned int* gcnt = (unsigned int*)alloc(1);

  k_prep<<<1346, 256, 0, stream>>>(D, DT, W3A1, W3A2, W3B, W4B,
                                   W3A1T, W3A2T, W3BT, W4BT, gsum, gcnt);
  k_edge<<<N, 256, 0, stream>>>(DT, dd, W1, W2, PT1, PT2, wd1, wd2);

  const float* c1 = mu0A1;
  const float* c2 = mu0A2;
  float* b1[2] = {muA1a, muA1b};
  float* b2[2] = {muA2a, muA2b};
  for (int it = 0; it < 4; it++) {
    k_iterA<<<dim3(64, 1, 2), 256, 0, stream>>>(PT1, PT2, c1, c2,
        b1[it & 1], b2[it & 1], wd1, wd2, dr, ddep,
        W3A1T, W3A2T, W4A1, W4A2, W5, W6);
    c1 = b1[it & 1];
    c2 = b2[it & 1];
  }

  const float* cB = mu0B;
  float* bB[2] = {muBa, muBb};
  for (int it = 0; it < 4; it++) {
    int flags = (it == 0 ? 1 : 0) | (it == 3 ? 2 : 0);
    k_iterB<<<64, 256, 0, stream>>>(PT1, cB, bB[it & 1],
        W3BT, W4BT, biasb, muA1b, muA2b,
        W7, gsum, gcnt, (float*)d_out, flags);
    cB = bB[it & 1];
  }
}

// Round 6
// 158.620 us; speedup vs baseline: 7.4095x; 2.7120x over previous
//
#include <hip/hip_runtime.h>
#include <math.h>

#define N 1024
#define M 128

// ---------------- prep: transpose D, transpose weights, zero accumulators ----------------
__global__ __launch_bounds__(256) void k_prep(const float* __restrict__ D, float* __restrict__ DT,
    const float* __restrict__ W3A1, const float* __restrict__ W3A2,
    const float* __restrict__ W3B, const float* __restrict__ W4B,
    float* __restrict__ oA1, float* __restrict__ oA2,
    float* __restrict__ oB, float* __restrict__ o4B,
    float* __restrict__ gsum, unsigned int* __restrict__ gcnt) {
  int bx = blockIdx.x, t = threadIdx.x;
  if (bx < 1024) {
    __shared__ float tile[32 * 33];
    int tx = t & 31, ty = t >> 5;
    int bxx = (bx & 31) * 32, by = (bx >> 5) * 32;
#pragma unroll
    for (int i = 0; i < 4; i++)
      tile[(ty + i * 8) * 33 + tx] = D[(size_t)(by + ty + i * 8) * N + bxx + tx];
    __syncthreads();
#pragma unroll
    for (int i = 0; i < 4; i++)
      DT[(size_t)(bxx + ty + i * 8) * N + by + tx] = tile[tx * 33 + ty + i * 8];
  } else if (bx < 1345) {
    int idx = (bx - 1024) * 256 + t;
    const float* in = nullptr; float* op = nullptr; int cols = 0, o = 0;
    if (idx < 16512)      { in = W3A1; op = oA1; cols = 129; o = idx; }
    else if (idx < 33024) { in = W3A2; op = oA2; cols = 129; o = idx - 16512; }
    else if (idx < 49408) { in = W3B;  op = oB;  cols = 128; o = idx - 33024; }
    else if (idx < 82176) { in = W4B;  op = o4B; cols = 256; o = idx - 49408; }
    if (in) { int r = o & 127, c = o >> 7; op[o] = in[r * cols + c]; }
  } else {
    if (t == 0) { *gsum = 0.f; *gcnt = 0u; }
  }
}

// ---------------- block reductions ----------------
__device__ __forceinline__ float blk_max(float v, float* red, int t) {
#pragma unroll
  for (int o = 32; o; o >>= 1) v = fmaxf(v, __shfl_xor(v, o));
  __syncthreads();
  if ((t & 63) == 0) red[t >> 6] = v;
  __syncthreads();
  return fmaxf(fmaxf(red[0], red[1]), fmaxf(red[2], red[3]));
}
__device__ __forceinline__ float blk_sum(float v, float* red, int t) {
#pragma unroll
  for (int o = 32; o; o >>= 1) v += __shfl_xor(v, o);
  __syncthreads();
  if ((t & 63) == 0) red[t >> 6] = v;
  __syncthreads();
  return red[0] + red[1] + red[2] + red[3];
}

// ---------------- edge scores + dual softmax + wd ----------------
// G_scaled = G_raw/1000 exactly (relu positively homogeneous) -> one MLP pass, two temps.
__global__ __launch_bounds__(256) void k_edge(const float* __restrict__ DT,
                                              const float* __restrict__ dd,
                                              const float* __restrict__ W1,
                                              const float* __restrict__ W2,
                                              float* __restrict__ PT1, float* __restrict__ PT2,
                                              float* __restrict__ wd1, float* __restrict__ wd2) {
  __shared__ float4 wp[128];
  __shared__ float red[4];
  int t = threadIdx.x, v = blockIdx.x;
  if (t < 128) {
    float4 p;
    p.x = W2[t * 3 + 0]; p.y = W2[t * 3 + 1]; p.z = W2[t * 3 + 2]; p.w = W1[t];
    wp[t] = p;
  }
  __syncthreads();
  float yv = dd[v];
  float x[4], z[4], g[4] = {0.f, 0.f, 0.f, 0.f};
#pragma unroll
  for (int i = 0; i < 4; i++) {
    int u = t + i * 256;
    x[i] = DT[(size_t)v * N + u];
    z[i] = dd[u];
  }
#pragma unroll 2
  for (int k = 0; k < 128; k++) {
    float4 wk = wp[k];
    float cv = yv * wk.z;
#pragma unroll
    for (int i = 0; i < 4; i++) {
      float h = fmaf(x[i], wk.x, fmaf(z[i], wk.y, cv));
      g[i] = fmaf(fmaxf(h, 0.f), wk.w, g[i]);
    }
  }
#pragma unroll
  for (int i = 0; i < 4; i++)
    if (t + i * 256 == v) g[i] = -INFINITY;
  float m = fmaxf(fmaxf(g[0], g[1]), fmaxf(g[2], g[3]));
  m = blk_max(m, red, t);
  float er[4], es[4], sr = 0.f, ss = 0.f;
#pragma unroll
  for (int i = 0; i < 4; i++) {
    er[i] = expf((g[i] - m) * 0.1f);     // raw: /TAU
    es[i] = expf((g[i] - m) * 1e-4f);    // scaled: /(1000*TAU)
    sr += er[i]; ss += es[i];
  }
  sr = blk_sum(sr, red, t);
  ss = blk_sum(ss, red, t);
  float ir = 1.f / sr, is = 1.f / ss;
  float a1 = 0.f, a2 = 0.f;
#pragma unroll
  for (int i = 0; i < 4; i++) {
    int u = t + i * 256;
    float pr = er[i] * ir, ps = es[i] * is;
    PT2[(size_t)v * N + u] = pr;
    PT1[(size_t)v * N + u] = ps;
    a1 += ps * x[i];
    a2 += pr * x[i];
  }
  a1 = blk_sum(a1, red, t);
  a2 = blk_sum(a2, red, t);
  if (t == 0) { wd1[v] = a1; wd2[v] = a2; }
}

// ---------------- GEMM core: 4 rows/block, full K, 8-way K-split across threads ----------------
// smem: As[4*1024] (16KB) | CsP[8*512] (16KB) | swd[4]
// After: Cred[512] = reduced C, stored in As region (reused).
__device__ __forceinline__ void gemm4(const float* __restrict__ PT,
                                      const float* __restrict__ cur,
                                      float* __restrict__ As, float* __restrict__ CsP,
                                      int r0, int t) {
  // stage 4 A rows, row-major (coalesced float4 copy)
#pragma unroll
  for (int i = 0; i < 4; i++) {
    int idx = t + i * 256;
    int row = idx >> 8, c4 = idx & 255;
    ((float4*)As)[row * 256 + c4] = *((const float4*)(PT + (size_t)(r0 + row) * N) + c4);
  }
  __syncthreads();
  const int kc = t >> 5;        // 0..7: K-slice of 128
  const int cg = t & 31;        // col group *4
  const int u0 = kc * 128;
  float4 acc0 = {0,0,0,0}, acc1 = {0,0,0,0}, acc2 = {0,0,0,0}, acc3 = {0,0,0,0};
  const float* mub = cur + (size_t)u0 * M + cg * 4;
  const float* a0p = As + u0;
  const float* a1p = As + 1024 + u0;
  const float* a2p = As + 2048 + u0;
  const float* a3p = As + 3072 + u0;
#pragma unroll 2
  for (int uu = 0; uu < 128; uu += 4) {
    float4 a0 = *(const float4*)&a0p[uu];
    float4 a1 = *(const float4*)&a1p[uu];
    float4 a2 = *(const float4*)&a2p[uu];
    float4 a3 = *(const float4*)&a3p[uu];
    float4 b0 = *(const float4*)&mub[(size_t)(uu + 0) * M];
    float4 b1 = *(const float4*)&mub[(size_t)(uu + 1) * M];
    float4 b2 = *(const float4*)&mub[(size_t)(uu + 2) * M];
    float4 b3 = *(const float4*)&mub[(size_t)(uu + 3) * M];
#define FMA4(ACC, AV) \
    ACC.x = fmaf(AV.x, b0.x, ACC.x); ACC.y = fmaf(AV.x, b0.y, ACC.y); \
    ACC.z = fmaf(AV.x, b0.z, ACC.z); ACC.w = fmaf(AV.x, b0.w, ACC.w); \
    ACC.x = fmaf(AV.y, b1.x, ACC.x); ACC.y = fmaf(AV.y, b1.y, ACC.y); \
    ACC.z = fmaf(AV.y, b1.z, ACC.z); ACC.w = fmaf(AV.y, b1.w, ACC.w); \
    ACC.x = fmaf(AV.z, b2.x, ACC.x); ACC.y = fmaf(AV.z, b2.y, ACC.y); \
    ACC.z = fmaf(AV.z, b2.z, ACC.z); ACC.w = fmaf(AV.z, b2.w, ACC.w); \
    ACC.x = fmaf(AV.w, b3.x, ACC.x); ACC.y = fmaf(AV.w, b3.y, ACC.y); \
    ACC.z = fmaf(AV.w, b3.z, ACC.z); ACC.w = fmaf(AV.w, b3.w, ACC.w);
    FMA4(acc0, a0) FMA4(acc1, a1) FMA4(acc2, a2) FMA4(acc3, a3)
#undef FMA4
  }
  float* cp = CsP + kc * 512 + cg * 4;
  *(float4*)&cp[0]   = acc0;
  *(float4*)&cp[128] = acc1;
  *(float4*)&cp[256] = acc2;
  *(float4*)&cp[384] = acc3;
  __syncthreads();
  // reduce 8 K-slices -> Cred[512] (stored at As)
#pragma unroll
  for (int i = 0; i < 2; i++) {
    int j = t + i * 256;
    float s = 0.f;
#pragma unroll
    for (int s8 = 0; s8 < 8; s8++) s += CsP[s8 * 512 + j];
    As[j] = s;
  }
}

// ---------------- fused A-iteration ----------------
__global__ __launch_bounds__(256) void k_iterA(
    const float* __restrict__ PT1, const float* __restrict__ PT2,
    const float* __restrict__ cur1, const float* __restrict__ cur2,
    float* __restrict__ nxt1, float* __restrict__ nxt2,
    const float* __restrict__ wd1, const float* __restrict__ wd2,
    const float* __restrict__ dr, const float* __restrict__ ddep,
    const float* __restrict__ W3A1T, const float* __restrict__ W3A2T,
    const float* __restrict__ W4A1, const float* __restrict__ W4A2,
    const float* __restrict__ W5, const float* __restrict__ W6) {
  __shared__ float smem[4096 + 4096 + 4];
  float* As = smem;
  float* CsP = smem + 4096;
  float* swd = smem + 8192;
  int z = blockIdx.z;
  const float* PT = z ? PT2 : PT1;
  const float* cur = z ? cur2 : cur1;
  float* nxt = z ? nxt2 : nxt1;
  const float* wdv = z ? wd2 : wd1;
  const float* dist = z ? ddep : dr;
  const float* W3T = z ? W3A2T : W3A1T;
  const float* W4c = z ? W4A2 : W4A1;
  const float* Wg = z ? W6 : W5;
  int t = threadIdx.x, r0 = blockIdx.x * 4;

  gemm4(PT, cur, As, CsP, r0, t);
  // swd[row] = wd[row]*relu(mu_row . Wg)  (runs in same region as reduce)
  {
    int row = t >> 6, l = t & 63;
    const float* mo = cur + (size_t)(r0 + row) * M;
    float sp = fmaf(mo[l], Wg[l], mo[l + 64] * Wg[l + 64]);
#pragma unroll
    for (int o = 32; o; o >>= 1) sp += __shfl_xor(sp, o);
    if (l == 0) swd[row] = wdv[r0 + row] * fmaxf(sp, 0.f);
  }
  __syncthreads();
  float* Cred = As;

  int col = t & 127, ra = t >> 7;   // rows ra and ra+2
  float accA = 0.f, accB = 0.f;
  const float* wcol = W3T + 128 + col;   // W3T rows 1..128
#pragma unroll 4
  for (int m = 0; m < 128; m += 4) {
    float4 c0 = *(const float4*)&Cred[ra * 128 + m];
    float4 c1 = *(const float4*)&Cred[(ra + 2) * 128 + m];
    float w0 = wcol[(m + 0) * 128], w1 = wcol[(m + 1) * 128];
    float w2 = wcol[(m + 2) * 128], w3 = wcol[(m + 3) * 128];
    accA = fmaf(c0.x, w0, fmaf(c0.y, w1, fmaf(c0.z, w2, fmaf(c0.w, w3, accA))));
    accB = fmaf(c1.x, w0, fmaf(c1.y, w1, fmaf(c1.z, w2, fmaf(c1.w, w3, accB))));
  }
  float w30 = W3T[col], w4 = W4c[col];
  float o0 = fmaxf(fmaf(swd[ra], w30, fmaf(dist[r0 + ra], w4, accA)), 0.f);
  float o1 = fmaxf(fmaf(swd[ra + 2], w30, fmaf(dist[r0 + ra + 2], w4, accB)), 0.f);
  nxt[(size_t)(r0 + ra) * M + col] = o0;
  nxt[(size_t)(r0 + ra + 2) * M + col] = o1;
}

// ---------------- fused B-iteration ----------------
__global__ __launch_bounds__(256) void k_iterB(
    const float* __restrict__ PT1, const float* __restrict__ cur, float* __restrict__ nxt,
    const float* __restrict__ W3BT, const float* __restrict__ W4BT, float* __restrict__ biasb,
    const float* __restrict__ A1f, const float* __restrict__ A2f,
    const float* __restrict__ W7, float* __restrict__ gsum, unsigned int* __restrict__ gcnt,
    float* __restrict__ out, int flags) {
  __shared__ float smem[4096 + 4096 + 4];
  float* As = smem;
  float* CsP = smem + 4096;
  float* red = smem + 8192;
  int t = threadIdx.x, r0 = blockIdx.x * 4;

  gemm4(PT1, cur, As, CsP, r0, t);
  __syncthreads();
  float* Cred = As;

  int col = t & 127, ra = t >> 7;   // rows ra and ra+2
  // bias: iter0 computes+stores, later iters load
  float bv0, bv1;
  if (flags & 1) {
    bv0 = 0.f; bv1 = 0.f;
    const float* a1a = A1f + (size_t)(r0 + ra) * M;
    const float* a1b = A1f + (size_t)(r0 + ra + 2) * M;
#pragma unroll 4
    for (int c = 0; c < 128; c++) {
      float wv = W4BT[c * 128 + col];
      bv0 = fmaf(a1a[c], wv, bv0);
      bv1 = fmaf(a1b[c], wv, bv1);
    }
    const float* a2a = A2f + (size_t)(r0 + ra) * M;
    const float* a2b = A2f + (size_t)(r0 + ra + 2) * M;
#pragma unroll 4
    for (int c = 0; c < 128; c++) {
      float wv = W4BT[(c + 128) * 128 + col];
      bv0 = fmaf(a2a[c], wv, bv0);
      bv1 = fmaf(a2b[c], wv, bv1);
    }
    biasb[(size_t)(r0 + ra) * M + col] = bv0;
    biasb[(size_t)(r0 + ra + 2) * M + col] = bv1;
  } else {
    bv0 = biasb[(size_t)(r0 + ra) * M + col];
    bv1 = biasb[(size_t)(r0 + ra + 2) * M + col];
  }

  float accA = 0.f, accB = 0.f;
  const float* wcol = W3BT + col;
#pragma unroll 4
  for (int m = 0; m < 128; m += 4) {
    float4 c0 = *(const float4*)&Cred[ra * 128 + m];
    float4 c1 = *(const float4*)&Cred[(ra + 2) * 128 + m];
    float w0 = wcol[(m + 0) * 128], w1 = wcol[(m + 1) * 128];
    float w2 = wcol[(m + 2) * 128], w3 = wcol[(m + 3) * 128];
    accA = fmaf(c0.x, w0, fmaf(c0.y, w1, fmaf(c0.z, w2, fmaf(c0.w, w3, accA))));
    accB = fmaf(c1.x, w0, fmaf(c1.y, w1, fmaf(c1.z, w2, fmaf(c1.w, w3, accB))));
  }
  float o0 = fmaxf(accA + bv0, 0.f);
  float o1 = fmaxf(accB + bv1, 0.f);

  if (!(flags & 2)) {
    nxt[(size_t)(r0 + ra) * M + col] = o0;
    nxt[(size_t)(r0 + ra + 2) * M + col] = o1;
  } else {
    // final: relu(W7 . colsum(mu)) via cross-block atomic reduce
    float s = (o0 + o1) * W7[col];
#pragma unroll
    for (int off = 32; off; off >>= 1) s += __shfl_xor(s, off);
    __syncthreads();
    if ((t & 63) == 0) red[t >> 6] = s;
    __syncthreads();
    if (t == 0) {
      float bs = red[0] + red[1] + red[2] + red[3];
      atomicAdd(gsum, bs);
      __threadfence();
      unsigned int old = atomicAdd(gcnt, 1u);
      if (old == 255u) {
        float tot = atomicAdd(gsum, 0.f);
        out[0] = fmaxf(tot, 0.f);
      }
    }
  }
}

extern "C" void kernel_launch(void* const* d_in, const int* in_sizes, int n_in,
                              void* d_out, int out_size, void* d_ws, size_t ws_size,
                              hipStream_t stream) {
  (void)in_sizes; (void)n_in; (void)out_size; (void)ws_size;
  const float* D     = (const float*)d_in[0];
  const float* dd    = (const float*)d_in[1];
  const float* dr    = (const float*)d_in[2];
  const float* ddep  = (const float*)d_in[3];
  const float* mu0A1 = (const float*)d_in[4];
  const float* mu0A2 = (const float*)d_in[5];
  const float* mu0B  = (const float*)d_in[6];
  const float* W1    = (const float*)d_in[7];
  const float* W2    = (const float*)d_in[8];
  const float* W3A1  = (const float*)d_in[9];
  const float* W3A2  = (const float*)d_in[10];
  const float* W4A1  = (const float*)d_in[11];
  const float* W4A2  = (const float*)d_in[12];
  const float* W3B   = (const float*)d_in[13];
  const float* W4B   = (const float*)d_in[14];
  const float* W5    = (const float*)d_in[15];
  const float* W6    = (const float*)d_in[16];
  const float* W7    = (const float*)d_in[17];

  float* w = (float*)d_ws;
  size_t o = 0;
  auto alloc = [&](size_t n) { float* p = w + o; o += n; return p; };
  float* DT    = alloc((size_t)N * N);
  float* PT1   = alloc((size_t)N * N);
  float* PT2   = alloc((size_t)N * N);
  float* wd1   = alloc(N);
  float* wd2   = alloc(N);
  float* W3A1T = alloc(129 * 128);
  float* W3A2T = alloc(129 * 128);
  float* W3BT  = alloc(128 * 128);
  float* W4BT  = alloc(256 * 128);
  float* muA1a = alloc((size_t)N * M); float* muA1b = alloc((size_t)N * M);
  float* muA2a = alloc((size_t)N * M); float* muA2b = alloc((size_t)N * M);
  float* muBa  = alloc((size_t)N * M); float* muBb  = alloc((size_t)N * M);
  float* biasb = alloc((size_t)N * M);
  float* gsum  = alloc(1);
  unsigned int* gcnt = (unsigned int*)alloc(1);

  k_prep<<<1346, 256, 0, stream>>>(D, DT, W3A1, W3A2, W3B, W4B,
                                   W3A1T, W3A2T, W3BT, W4BT, gsum, gcnt);
  k_edge<<<N, 256, 0, stream>>>(DT, dd, W1, W2, PT1, PT2, wd1, wd2);

  const float* c1 = mu0A1;
  const float* c2 = mu0A2;
  float* b1[2] = {muA1a, muA1b};
  float* b2[2] = {muA2a, muA2b};
  for (int it = 0; it < 4; it++) {
    k_iterA<<<dim3(256, 1, 2), 256, 0, stream>>>(PT1, PT2, c1, c2,
        b1[it & 1], b2[it & 1], wd1, wd2, dr, ddep,
        W3A1T, W3A2T, W4A1, W4A2, W5, W6);
    c1 = b1[it & 1];
    c2 = b2[it & 1];
  }

  const float* cB = mu0B;
  float* bB[2] = {muBa, muBb};
  for (int it = 0; it < 4; it++) {
    int flags = (it == 0 ? 1 : 0) | (it == 3 ? 2 : 0);
    k_iterB<<<256, 256, 0, stream>>>(PT1, cB, bB[it & 1],
        W3BT, W4BT, biasb, muA1b, muA2b,
        W7, gsum, gcnt, (float*)d_out, flags);
    cB = bB[it & 1];
  }
}